// Round 5
// baseline (1749.811 us; speedup 1.0000x reference)
//
#include <hip/hip_runtime.h>
#include <math.h>

#define N_NODES 100000
#define N_EDGES 640000
#define IN_DIM 64
#define HID 128
#define NGRAPH 128

typedef __bf16 bf16x2 __attribute__((ext_vector_type(2)));
typedef __bf16 bf16x4 __attribute__((ext_vector_type(4)));
typedef __bf16 bf16x8 __attribute__((ext_vector_type(8)));
typedef float f32x4 __attribute__((ext_vector_type(4)));

#define LDST 136  // bf16 elements per LDS row: 272 B, 16B-aligned, breaks pow2 stride

// ---------------------------------------------------------------------------
// fma helper (used by k_input only)
// ---------------------------------------------------------------------------
__device__ __forceinline__ void fma44(const float4 A[4], const float4 B[4], float acc[4][4]) {
#pragma unroll
  for (int i2 = 0; i2 < 4; ++i2) {
    acc[i2][0] += A[i2].x*B[0].x + A[i2].y*B[1].x + A[i2].z*B[2].x + A[i2].w*B[3].x;
    acc[i2][1] += A[i2].x*B[0].y + A[i2].y*B[1].y + A[i2].z*B[2].y + A[i2].w*B[3].y;
    acc[i2][2] += A[i2].x*B[0].z + A[i2].y*B[1].z + A[i2].z*B[2].z + A[i2].w*B[3].z;
    acc[i2][3] += A[i2].x*B[0].w + A[i2].y*B[1].w + A[i2].z*B[2].w + A[i2].w*B[3].w;
  }
}

// ---------------------------------------------------------------------------
// Kernel 1: h = relu(x @ W_in.T + b_in)
// ---------------------------------------------------------------------------
__global__ __launch_bounds__(256) void k_input(const float* __restrict__ x,
                                               const float* __restrict__ W,
                                               const float* __restrict__ b,
                                               float* __restrict__ h) {
  __shared__ float wS[64][132];
  __shared__ float xS[32][68];
  int t = threadIdx.x;
  int nb = blockIdx.x * 32;
#pragma unroll
  for (int i = 0; i < 8; ++i) {
    int idx4 = i * 256 + t;
    int j = idx4 >> 4, kq = idx4 & 15;
    float4 v = ((const float4*)W)[j * 16 + kq];
    wS[4*kq+0][j] = v.x; wS[4*kq+1][j] = v.y; wS[4*kq+2][j] = v.z; wS[4*kq+3][j] = v.w;
  }
#pragma unroll
  for (int i = 0; i < 2; ++i) {
    int idx4 = i * 256 + t;
    int n = idx4 >> 4, kq = idx4 & 15;
    float4 v = ((const float4*)x)[(nb + n) * 16 + kq];
    *((float4*)&xS[n][4*kq]) = v;
  }
  __syncthreads();
  int bq = t & 31, a = t >> 5;
  float acc[4][4] = {};
#pragma unroll
  for (int kk4 = 0; kk4 < 16; ++kk4) {
    float4 A[4], B[4];
#pragma unroll
    for (int i2 = 0; i2 < 4; ++i2) A[i2] = *((const float4*)&xS[4*a+i2][4*kk4]);
#pragma unroll
    for (int c = 0; c < 4; ++c) B[c] = *((const float4*)&wS[4*kk4+c][4*bq]);
    fma44(A, B, acc);
  }
  float4 bb = ((const float4*)b)[bq];
  float ba[4] = {bb.x, bb.y, bb.z, bb.w};
#pragma unroll
  for (int i2 = 0; i2 < 4; ++i2) {
    float4 o;
    o.x = fmaxf(acc[i2][0] + ba[0], 0.f);
    o.y = fmaxf(acc[i2][1] + ba[1], 0.f);
    o.z = fmaxf(acc[i2][2] + ba[2], 0.f);
    o.w = fmaxf(acc[i2][3] + ba[3], 0.f);
    ((float4*)h)[(nb + 4*a + i2) * 32 + bq] = o;
  }
}

// ---------------------------------------------------------------------------
// CSR build: histogram -> scan -> fill
// ---------------------------------------------------------------------------
__global__ __launch_bounds__(256) void k_hist(const int* __restrict__ dst,
                                              int* __restrict__ deg) {
  int e = blockIdx.x * 256 + threadIdx.x;
  if (e < N_EDGES) atomicAdd(&deg[dst[e]], 1);
}

#define SCAN_CHUNK 4096
#define SCAN_NB 25

__global__ __launch_bounds__(256) void k_scan_part(const int* __restrict__ deg,
                                                   int* __restrict__ bsum) {
  __shared__ int red[256];
  int t = threadIdx.x, b = blockIdx.x;
  int base = b * SCAN_CHUNK + t * 16;
  int s = 0;
#pragma unroll
  for (int i = 0; i < 16; ++i) {
    int idx = base + i;
    if (idx < N_NODES) s += deg[idx];
  }
  red[t] = s;
  __syncthreads();
  for (int off = 128; off > 0; off >>= 1) {
    if (t < off) red[t] += red[t + off];
    __syncthreads();
  }
  if (t == 0) bsum[b] = red[0];
}

__global__ void k_scan_mid(const int* __restrict__ bsum, int* __restrict__ boff,
                           int* __restrict__ rowstart) {
  if (threadIdx.x == 0) {
    int run = 0;
    for (int i = 0; i < SCAN_NB; ++i) { boff[i] = run; run += bsum[i]; }
    rowstart[N_NODES] = run;
  }
}

__global__ __launch_bounds__(256) void k_scan_final(const int* __restrict__ deg,
                                                    const int* __restrict__ boff,
                                                    int* __restrict__ rowstart) {
  __shared__ int ts[256];
  int t = threadIdx.x, b = blockIdx.x;
  int base = b * SCAN_CHUNK + t * 16;
  int v[16];
  int s = 0;
#pragma unroll
  for (int i = 0; i < 16; ++i) {
    int idx = base + i;
    v[i] = (idx < N_NODES) ? deg[idx] : 0;
    s += v[i];
  }
  ts[t] = s;
  __syncthreads();
  for (int off = 1; off < 256; off <<= 1) {
    int add = (t >= off) ? ts[t - off] : 0;
    __syncthreads();
    ts[t] += add;
    __syncthreads();
  }
  int run = boff[b] + ts[t] - s;
#pragma unroll
  for (int i = 0; i < 16; ++i) {
    int idx = base + i;
    if (idx < N_NODES) rowstart[idx] = run;
    run += v[i];
  }
}

__global__ __launch_bounds__(256) void k_fill(const int* __restrict__ src,
                                              const int* __restrict__ dst,
                                              int* __restrict__ cursor,
                                              int* __restrict__ srcSorted) {
  int e = blockIdx.x * 256 + threadIdx.x;
  if (e >= N_EDGES) return;
  int d = dst[e];
  int p = atomicAdd(&cursor[d], 1);
  srcSorted[p] = src[e];
}

// ---------------------------------------------------------------------------
// One-time weight split fp32 -> bf16 (hi, lo). Layout preserved: [mat][j][k]
// mats: 0=W_f, 1=U_f, 2=W_h, 3=U_h
// ---------------------------------------------------------------------------
__global__ __launch_bounds__(256) void k_wsplit(const float* __restrict__ W0,
                                                const float* __restrict__ W1,
                                                const float* __restrict__ W2,
                                                const float* __restrict__ W3,
                                                __bf16* __restrict__ Whi,
                                                __bf16* __restrict__ Wlo) {
  int id = blockIdx.x * 256 + threadIdx.x;  // 65536 total
  int mat = id >> 14, idx = id & 16383;
  const float* W = (mat == 0) ? W0 : (mat == 1) ? W1 : (mat == 2) ? W2 : W3;
  float v = W[idx];
  __bf16 hi = (__bf16)v;
  Whi[id] = hi;
  Wlo[id] = (__bf16)(v - (float)hi);
}

// ---------------------------------------------------------------------------
// Fused gather + MGU update. Ping-pong: reads hin, writes hout.
//   gather: m_i = sum_{j->i} hin[srcSorted[j]]  (per-wave, 8 nodes/wave)
//   MGU: f = sigmoid(m@Wf.T + h@Uf.T + bf); hh = tanh(m@Wh.T + (f*h)@Uh.T + bh)
//        hout = (1-f)*h + f*hh
// 32 nodes/block. LDS = 4 arrays x [32][136] bf16 = 34,816 B -> 4 blocks/CU,
// 16 waves/CU. g = f*h overwrites the h tile in place between two barriers.
// MFMA layouts (verified m89/m91/m120):
//   A-frag: A[m=lane&15][k=(lane>>4)*8 + j]
//   B-frag: W[j=lane&15][k consecutive] (row-major, no transpose)
//   C/D:    col = lane&15, row = (lane>>4)*4 + reg
// ---------------------------------------------------------------------------
__global__ __launch_bounds__(256) void k_mgu(const float* __restrict__ hin,
                                             float* __restrict__ hout,
                                             const int* __restrict__ rowstart,
                                             const int* __restrict__ srcSorted,
                                             const __bf16* __restrict__ Whi,
                                             const __bf16* __restrict__ Wlo,
                                             const float* __restrict__ bfp,
                                             const float* __restrict__ bhp) {
  __shared__ __bf16 mHi[32 * LDST], mLo[32 * LDST];
  __shared__ __bf16 hHi[32 * LDST], hLo[32 * LDST];  // becomes g after f-gate
  const int t = threadIdx.x;
  const int nb = blockIdx.x * 32;
  const int w = t >> 6, l = t & 63;

  // ---- stage h tile (hin), split bf16 hi/lo ----
#pragma unroll
  for (int i = 0; i < 4; ++i) {
    int idx4 = i * 256 + t;
    int n = idx4 >> 5, kq = idx4 & 31;
    float4 vh = ((const float4*)hin)[(nb + n) * 32 + kq];
    bf16x4 hh, hl;
    hh[0] = (__bf16)vh.x; hl[0] = (__bf16)(vh.x - (float)hh[0]);
    hh[1] = (__bf16)vh.y; hl[1] = (__bf16)(vh.y - (float)hh[1]);
    hh[2] = (__bf16)vh.z; hl[2] = (__bf16)(vh.z - (float)hh[2]);
    hh[3] = (__bf16)vh.w; hl[3] = (__bf16)(vh.w - (float)hh[3]);
    int e0 = n * LDST + 4 * kq;
    *(bf16x4*)&hHi[e0] = hh; *(bf16x4*)&hLo[e0] = hl;
  }

  // ---- gather m for 8 nodes per wave; split bf16 hi/lo into LDS ----
  const float2* h2 = (const float2*)hin;
#pragma unroll
  for (int i = 0; i < 8; ++i) {
    int node = nb + 8 * w + i;
    int j0 = rowstart[node], j1 = rowstart[node + 1];
    float2 a0 = {0.f, 0.f}, a1 = {0.f, 0.f};
    int j = j0;
    for (; j + 1 < j1; j += 2) {
      int s0 = srcSorted[j], s1 = srcSorted[j + 1];
      float2 v0 = h2[s0 * 64 + l];
      float2 v1 = h2[s1 * 64 + l];
      a0.x += v0.x; a0.y += v0.y;
      a1.x += v1.x; a1.y += v1.y;
    }
    if (j < j1) {
      int s0 = srcSorted[j];
      float2 v0 = h2[s0 * 64 + l];
      a0.x += v0.x; a0.y += v0.y;
    }
    float sx = a0.x + a1.x, sy = a0.y + a1.y;
    __bf16 hx = (__bf16)sx, hy = (__bf16)sy;
    bf16x2 vh2 = {hx, hy};
    bf16x2 vl2 = {(__bf16)(sx - (float)hx), (__bf16)(sy - (float)hy)};
    int e0 = (8 * w + i) * LDST + 2 * l;
    *(bf16x2*)&mHi[e0] = vh2;
    *(bf16x2*)&mLo[e0] = vl2;
  }
  __syncthreads();

  const int lj = l & 15, q = l >> 4;

  float bfj[2], bhj[2];
#pragma unroll
  for (int ct = 0; ct < 2; ++ct) {
    int j = (2 * w + ct) * 16 + lj;
    bfj[ct] = bfp[j];
    bhj[ct] = bhp[j];
  }

  f32x4 acc[2][2] = {};

  // ---- phase A: z_f = m@Wf.T + h@Uf.T ----
#pragma unroll
  for (int kc = 0; kc < 128; kc += 32) {
    bf16x8 amh[2], aml[2], ahh[2], ahl[2];
#pragma unroll
    for (int rt = 0; rt < 2; ++rt) {
      int e0 = (rt * 16 + lj) * LDST + kc + q * 8;
      amh[rt] = *(const bf16x8*)&mHi[e0];
      aml[rt] = *(const bf16x8*)&mLo[e0];
      ahh[rt] = *(const bf16x8*)&hHi[e0];
      ahl[rt] = *(const bf16x8*)&hLo[e0];
    }
    bf16x8 bwh[2], bwl[2], buh[2], bul[2];
#pragma unroll
    for (int ct = 0; ct < 2; ++ct) {
      int off = ((2 * w + ct) * 16 + lj) * 128 + kc + q * 8;
      bwh[ct] = *(const bf16x8*)&Whi[off];            // W_f hi
      bwl[ct] = *(const bf16x8*)&Wlo[off];
      buh[ct] = *(const bf16x8*)&Whi[16384 + off];    // U_f hi
      bul[ct] = *(const bf16x8*)&Wlo[16384 + off];
    }
#pragma unroll
    for (int rt = 0; rt < 2; ++rt)
#pragma unroll
      for (int ct = 0; ct < 2; ++ct) {
        f32x4 a = acc[rt][ct];
        a = __builtin_amdgcn_mfma_f32_16x16x32_bf16(amh[rt], bwh[ct], a, 0, 0, 0);
        a = __builtin_amdgcn_mfma_f32_16x16x32_bf16(amh[rt], bwl[ct], a, 0, 0, 0);
        a = __builtin_amdgcn_mfma_f32_16x16x32_bf16(aml[rt], bwh[ct], a, 0, 0, 0);
        a = __builtin_amdgcn_mfma_f32_16x16x32_bf16(ahh[rt], buh[ct], a, 0, 0, 0);
        a = __builtin_amdgcn_mfma_f32_16x16x32_bf16(ahh[rt], bul[ct], a, 0, 0, 0);
        a = __builtin_amdgcn_mfma_f32_16x16x32_bf16(ahl[rt], buh[ct], a, 0, 0, 0);
        acc[rt][ct] = a;
      }
  }

  // ---- transition: f = sigmoid(z_f + bf); g = f*h overwrites h tile ----
  __syncthreads();  // all phase-A reads of hHi/hLo complete
  float fv[2][2][4], hvv[2][2][4];
#pragma unroll
  for (int rt = 0; rt < 2; ++rt)
#pragma unroll
    for (int ct = 0; ct < 2; ++ct) {
      int j = (2 * w + ct) * 16 + lj;
#pragma unroll
      for (int r = 0; r < 4; ++r) {
        int nl = rt * 16 + q * 4 + r;
        float z = acc[rt][ct][r] + bfj[ct];
        float f = 1.f / (1.f + expf(-z));
        int he = nl * LDST + j;
        float hval = (float)hHi[he] + (float)hLo[he];
        float g = f * hval;
        __bf16 ghi = (__bf16)g;
        hHi[he] = ghi;
        hLo[he] = (__bf16)(g - (float)ghi);
        fv[rt][ct][r] = f;
        hvv[rt][ct][r] = hval;
        acc[rt][ct][r] = 0.f;
      }
    }
  __syncthreads();

  // ---- phase B: z_h = m@Wh.T + g@Uh.T ----
#pragma unroll
  for (int kc = 0; kc < 128; kc += 32) {
    bf16x8 amh[2], aml[2], agh[2], agl[2];
#pragma unroll
    for (int rt = 0; rt < 2; ++rt) {
      int e0 = (rt * 16 + lj) * LDST + kc + q * 8;
      amh[rt] = *(const bf16x8*)&mHi[e0];
      aml[rt] = *(const bf16x8*)&mLo[e0];
      agh[rt] = *(const bf16x8*)&hHi[e0];
      agl[rt] = *(const bf16x8*)&hLo[e0];
    }
    bf16x8 bwh[2], bwl[2], buh[2], bul[2];
#pragma unroll
    for (int ct = 0; ct < 2; ++ct) {
      int off = ((2 * w + ct) * 16 + lj) * 128 + kc + q * 8;
      bwh[ct] = *(const bf16x8*)&Whi[2 * 16384 + off];  // W_h hi
      bwl[ct] = *(const bf16x8*)&Wlo[2 * 16384 + off];
      buh[ct] = *(const bf16x8*)&Whi[3 * 16384 + off];  // U_h hi
      bul[ct] = *(const bf16x8*)&Wlo[3 * 16384 + off];
    }
#pragma unroll
    for (int rt = 0; rt < 2; ++rt)
#pragma unroll
      for (int ct = 0; ct < 2; ++ct) {
        f32x4 a = acc[rt][ct];
        a = __builtin_amdgcn_mfma_f32_16x16x32_bf16(amh[rt], bwh[ct], a, 0, 0, 0);
        a = __builtin_amdgcn_mfma_f32_16x16x32_bf16(amh[rt], bwl[ct], a, 0, 0, 0);
        a = __builtin_amdgcn_mfma_f32_16x16x32_bf16(aml[rt], bwh[ct], a, 0, 0, 0);
        a = __builtin_amdgcn_mfma_f32_16x16x32_bf16(agh[rt], buh[ct], a, 0, 0, 0);
        a = __builtin_amdgcn_mfma_f32_16x16x32_bf16(agh[rt], bul[ct], a, 0, 0, 0);
        a = __builtin_amdgcn_mfma_f32_16x16x32_bf16(agl[rt], buh[ct], a, 0, 0, 0);
        acc[rt][ct] = a;
      }
  }

  // ---- epilogue: hout = (1-f)*h + f*tanh(z_h + bh) ----
#pragma unroll
  for (int rt = 0; rt < 2; ++rt)
#pragma unroll
    for (int ct = 0; ct < 2; ++ct) {
      int j = (2 * w + ct) * 16 + lj;
#pragma unroll
      for (int r = 0; r < 4; ++r) {
        float T = tanhf(acc[rt][ct][r] + bhj[ct]);
        float f = fv[rt][ct][r];
        float hn = (1.f - f) * hvv[rt][ct][r] + f * T;
        hout[(nb + rt * 16 + q * 4 + r) * 128 + j] = hn;
      }
    }
}

// ---------------------------------------------------------------------------
// Set2Set kernels
// ---------------------------------------------------------------------------
__global__ void k_bounds(const int* __restrict__ batch, int* __restrict__ startv) {
  int t = threadIdx.x;
  if (t > NGRAPH) return;
  int lo = 0, hi = N_NODES;
  while (lo < hi) { int mid = (lo + hi) >> 1; if (batch[mid] < t) lo = mid + 1; else hi = mid; }
  startv[t] = lo;
}

__global__ __launch_bounds__(256) void k_lstm(float* __restrict__ q_star,
                                              float* __restrict__ h_l,
                                              float* __restrict__ c_l,
                                              const float* __restrict__ w_ih,
                                              const float* __restrict__ w_hh,
                                              const float* __restrict__ b_ih,
                                              const float* __restrict__ b_hh) {
  int g = blockIdx.x, t = threadIdx.x;
  __shared__ float qsS[256];
  __shared__ float hlS[128];
  __shared__ float gateS[512];
  qsS[t] = q_star[g * 256 + t];
  if (t < 128) hlS[t] = h_l[g * 128 + t];
  __syncthreads();
  int w = t >> 6, l = t & 63;
  for (int jt = w; jt < 512; jt += 4) {
    const float* wi = w_ih + jt * 256;
    const float* wh = w_hh + jt * 128;
    float s = qsS[l] * wi[l] + qsS[l+64] * wi[l+64]
            + qsS[l+128] * wi[l+128] + qsS[l+192] * wi[l+192]
            + hlS[l] * wh[l] + hlS[l+64] * wh[l+64];
#pragma unroll
    for (int o = 32; o > 0; o >>= 1) s += __shfl_xor(s, o, 64);
    if (l == 0) gateS[jt] = s + b_ih[jt] + b_hh[jt];
  }
  __syncthreads();
  if (t < 128) {
    float gi = gateS[t], gf = gateS[128 + t], gg = gateS[256 + t], go = gateS[384 + t];
    float c = 1.f/(1.f+expf(-gf)) * c_l[g*128 + t] + 1.f/(1.f+expf(-gi)) * tanhf(gg);
    float hh = 1.f/(1.f+expf(-go)) * tanhf(c);
    c_l[g*128 + t] = c;
    h_l[g*128 + t] = hh;
    q_star[g*256 + t] = hh;
  }
}

__global__ __launch_bounds__(256) void k_attn1(const float* __restrict__ h,
                                               const float* __restrict__ q_star,
                                               const int* __restrict__ startv,
                                               float* __restrict__ e,
                                               float* __restrict__ gmax,
                                               float* __restrict__ gsum) {
  int g = blockIdx.x, t = threadIdx.x;
  __shared__ float qS[128];
  __shared__ float redM[4], redS[4];
  if (t < 128) qS[t] = q_star[g * 256 + t];
  __syncthreads();
  int s0 = startv[g], s1 = startv[g + 1];
  int w = t >> 6, l = t & 63;
  float mx = -INFINITY, sm = 0.f;
  for (int n = s0 + w; n < s1; n += 4) {
    float v = h[n*128 + l] * qS[l] + h[n*128 + 64 + l] * qS[64 + l];
#pragma unroll
    for (int o = 32; o > 0; o >>= 1) v += __shfl_xor(v, o, 64);
    if (l == 0) e[n] = v;
    float nm = fmaxf(mx, v);
    sm = sm * expf(mx - nm) + expf(v - nm);
    mx = nm;
  }
  if (l == 0) { redM[w] = mx; redS[w] = sm; }
  __syncthreads();
  if (t == 0) {
    float M = -INFINITY;
    for (int i = 0; i < 4; ++i) M = fmaxf(M, redM[i]);
    float S = 0.f;
    for (int i = 0; i < 4; ++i) if (redS[i] > 0.f) S += redS[i] * expf(redM[i] - M);
    gmax[g] = M; gsum[g] = S;
  }
}

__global__ __launch_bounds__(256) void k_attn2(const float* __restrict__ h,
                                               const float* __restrict__ e,
                                               const int* __restrict__ startv,
                                               const float* __restrict__ gmax,
                                               const float* __restrict__ gsum,
                                               float* __restrict__ q_star) {
  int g = blockIdx.x, t = threadIdx.x;
  int tj = t & 127, tn = t >> 7;
  int s0 = startv[g], s1 = startv[g + 1];
  float M = gmax[g];
  float sg = gsum[g];
  float inv = (sg > 0.f) ? 1.f / sg : 0.f;
  float acc = 0.f;
  for (int n = s0 + tn; n < s1; n += 2) {
    float aw = expf(e[n] - M) * inv;
    acc += aw * h[n*128 + tj];
  }
  __shared__ float red[256];
  red[t] = acc;
  __syncthreads();
  if (t < 128) q_star[g*256 + 128 + t] = red[t] + red[t + 128];
}

__global__ void k_pred(const float* __restrict__ q_star, const float* __restrict__ Wp,
                       const float* __restrict__ bp, float* __restrict__ out) {
  int g = threadIdx.x;
  float s = 0.f;
  for (int k = 0; k < 256; ++k) s += q_star[g*256 + k] * Wp[k];
  out[g] = s + bp[0];
}

// ---------------------------------------------------------------------------
extern "C" void kernel_launch(void* const* d_in, const int* in_sizes, int n_in,
                              void* d_out, int out_size, void* d_ws, size_t ws_size,
                              hipStream_t stream) {
  const float* x      = (const float*)d_in[0];
  const int*   ei     = (const int*)d_in[1];
  const int*   batch  = (const int*)d_in[2];
  const float* W_in   = (const float*)d_in[3];
  const float* b_in   = (const float*)d_in[4];
  const float* W_f    = (const float*)d_in[5];
  const float* U_f    = (const float*)d_in[6];
  const float* b_f    = (const float*)d_in[7];
  const float* W_h    = (const float*)d_in[8];
  const float* U_h    = (const float*)d_in[9];
  const float* b_h    = (const float*)d_in[10];
  const float* w_ih   = (const float*)d_in[11];
  const float* w_hh   = (const float*)d_in[12];
  const float* b_ih   = (const float*)d_in[13];
  const float* b_hh   = (const float*)d_in[14];
  const float* W_pred = (const float*)d_in[15];
  const float* b_pred = (const float*)d_in[16];
  float* out = (float*)d_out;

  char* ws = (char*)d_ws;
  float* hA     = (float*)(ws);                    // 51,200,000 B
  float* hB     = (float*)(ws + 51200000);         // 51,200,000 B
  float* e      = (float*)(ws + 102400000);        //    400,000 B (aliased below)
  float* q_star = (float*)(ws + 102800000);        //    131,072 B
  float* h_l    = (float*)(ws + 102931072);        //     65,536 B
  float* c_l    = (float*)(ws + 102996608);        //     65,536 B
  float* gmax   = (float*)(ws + 103062144);        //        512 B
  float* gsum   = (float*)(ws + 103062656);        //        512 B
  int*   startv = (int*)  (ws + 103063168);        //        528 B
  int*   rowstart = (int*)(ws + 103063808);        //    400,016 B
  int*   srcSorted= (int*)(ws + 103463824);        //  2,560,000 B
  int*   bsum   = (int*)  (ws + 106023824);        //        112 B
  int*   boff   = (int*)  (ws + 106023936);        //        112 B
  // 'e' buffer lifetimes: deg/cursor (CSR build) -> Whi/Wlo (MPNN loop,
  // 262,144 B <= 400,000) -> e scores (set2set)
  int*    deg    = (int*)e;
  int*    cursor = (int*)e;
  __bf16* Whi    = (__bf16*)(ws + 102400000);      //    131,072 B
  __bf16* Wlo    = (__bf16*)(ws + 102531072);      //    131,072 B

  const int* src = ei;
  const int* dst = ei + N_EDGES;

  // ---- CSR build (once; reused by all 3 MPNN steps) ----
  hipMemsetAsync(deg, 0, N_NODES * 4, stream);
  k_hist<<<(N_EDGES + 255) / 256, 256, 0, stream>>>(dst, deg);
  k_scan_part<<<SCAN_NB, 256, 0, stream>>>(deg, bsum);
  k_scan_mid<<<1, 32, 0, stream>>>(bsum, boff, rowstart);
  k_scan_final<<<SCAN_NB, 256, 0, stream>>>(deg, boff, rowstart);
  hipMemcpyAsync(cursor, rowstart, N_NODES * 4, hipMemcpyDeviceToDevice, stream);
  k_fill<<<(N_EDGES + 255) / 256, 256, 0, stream>>>(src, dst, cursor, srcSorted);

  // ---- one-time weight bf16 hi/lo split (overwrites deg/cursor region) ----
  k_wsplit<<<256, 256, 0, stream>>>(W_f, U_f, W_h, U_h, Whi, Wlo);

  k_input<<<N_NODES / 32, 256, 0, stream>>>(x, W_in, b_in, hA);

  // ping-pong: hA -> hB -> hA -> hB
  k_mgu<<<N_NODES / 32, 256, 0, stream>>>(hA, hB, rowstart, srcSorted, Whi, Wlo, b_f, b_h);
  k_mgu<<<N_NODES / 32, 256, 0, stream>>>(hB, hA, rowstart, srcSorted, Whi, Wlo, b_f, b_h);
  k_mgu<<<N_NODES / 32, 256, 0, stream>>>(hA, hB, rowstart, srcSorted, Whi, Wlo, b_f, b_h);
  float* hFin = hB;

  k_bounds<<<1, 256, 0, stream>>>(batch, startv);
  hipMemsetAsync(q_star, 0, 262144, stream);

  for (int s = 0; s < 3; ++s) {
    k_lstm<<<NGRAPH, 256, 0, stream>>>(q_star, h_l, c_l, w_ih, w_hh, b_ih, b_hh);
    k_attn1<<<NGRAPH, 256, 0, stream>>>(hFin, q_star, startv, e, gmax, gsum);
    k_attn2<<<NGRAPH, 256, 0, stream>>>(hFin, e, startv, gmax, gsum, q_star);
  }

  k_pred<<<1, 128, 0, stream>>>(q_star, W_pred, b_pred, out);
}

// Round 6
// 987.626 us; speedup vs baseline: 1.7717x; 1.7717x over previous
//
#include <hip/hip_runtime.h>
#include <math.h>

#define N_NODES 100000
#define N_EDGES 640000
#define IN_DIM 64
#define HID 128
#define NGRAPH 128

typedef __bf16 bf16x2 __attribute__((ext_vector_type(2)));
typedef __bf16 bf16x4 __attribute__((ext_vector_type(4)));
typedef __bf16 bf16x8 __attribute__((ext_vector_type(8)));
typedef float f32x4 __attribute__((ext_vector_type(4)));

#define LDST 136  // bf16 elements per LDS row: 272 B, 16B-aligned, breaks pow2 stride

// ---------------------------------------------------------------------------
// fma helper (used by k_input only)
// ---------------------------------------------------------------------------
__device__ __forceinline__ void fma44(const float4 A[4], const float4 B[4], float acc[4][4]) {
#pragma unroll
  for (int i2 = 0; i2 < 4; ++i2) {
    acc[i2][0] += A[i2].x*B[0].x + A[i2].y*B[1].x + A[i2].z*B[2].x + A[i2].w*B[3].x;
    acc[i2][1] += A[i2].x*B[0].y + A[i2].y*B[1].y + A[i2].z*B[2].y + A[i2].w*B[3].y;
    acc[i2][2] += A[i2].x*B[0].z + A[i2].y*B[1].z + A[i2].z*B[2].z + A[i2].w*B[3].z;
    acc[i2][3] += A[i2].x*B[0].w + A[i2].y*B[1].w + A[i2].z*B[2].w + A[i2].w*B[3].w;
  }
}

// ---------------------------------------------------------------------------
// Kernel 1: h = relu(x @ W_in.T + b_in)
// ---------------------------------------------------------------------------
__global__ __launch_bounds__(256) void k_input(const float* __restrict__ x,
                                               const float* __restrict__ W,
                                               const float* __restrict__ b,
                                               float* __restrict__ h) {
  __shared__ float wS[64][132];
  __shared__ float xS[32][68];
  int t = threadIdx.x;
  int nb = blockIdx.x * 32;
#pragma unroll
  for (int i = 0; i < 8; ++i) {
    int idx4 = i * 256 + t;
    int j = idx4 >> 4, kq = idx4 & 15;
    float4 v = ((const float4*)W)[j * 16 + kq];
    wS[4*kq+0][j] = v.x; wS[4*kq+1][j] = v.y; wS[4*kq+2][j] = v.z; wS[4*kq+3][j] = v.w;
  }
#pragma unroll
  for (int i = 0; i < 2; ++i) {
    int idx4 = i * 256 + t;
    int n = idx4 >> 4, kq = idx4 & 15;
    float4 v = ((const float4*)x)[(nb + n) * 16 + kq];
    *((float4*)&xS[n][4*kq]) = v;
  }
  __syncthreads();
  int bq = t & 31, a = t >> 5;
  float acc[4][4] = {};
#pragma unroll
  for (int kk4 = 0; kk4 < 16; ++kk4) {
    float4 A[4], B[4];
#pragma unroll
    for (int i2 = 0; i2 < 4; ++i2) A[i2] = *((const float4*)&xS[4*a+i2][4*kk4]);
#pragma unroll
    for (int c = 0; c < 4; ++c) B[c] = *((const float4*)&wS[4*kk4+c][4*bq]);
    fma44(A, B, acc);
  }
  float4 bb = ((const float4*)b)[bq];
  float ba[4] = {bb.x, bb.y, bb.z, bb.w};
#pragma unroll
  for (int i2 = 0; i2 < 4; ++i2) {
    float4 o;
    o.x = fmaxf(acc[i2][0] + ba[0], 0.f);
    o.y = fmaxf(acc[i2][1] + ba[1], 0.f);
    o.z = fmaxf(acc[i2][2] + ba[2], 0.f);
    o.w = fmaxf(acc[i2][3] + ba[3], 0.f);
    ((float4*)h)[(nb + 4*a + i2) * 32 + bq] = o;
  }
}

// ---------------------------------------------------------------------------
// CSR build: histogram -> scan -> fill
// ---------------------------------------------------------------------------
__global__ __launch_bounds__(256) void k_hist(const int* __restrict__ dst,
                                              int* __restrict__ deg) {
  int e = blockIdx.x * 256 + threadIdx.x;
  if (e < N_EDGES) atomicAdd(&deg[dst[e]], 1);
}

#define SCAN_CHUNK 4096
#define SCAN_NB 25

__global__ __launch_bounds__(256) void k_scan_part(const int* __restrict__ deg,
                                                   int* __restrict__ bsum) {
  __shared__ int red[256];
  int t = threadIdx.x, b = blockIdx.x;
  int base = b * SCAN_CHUNK + t * 16;
  int s = 0;
#pragma unroll
  for (int i = 0; i < 16; ++i) {
    int idx = base + i;
    if (idx < N_NODES) s += deg[idx];
  }
  red[t] = s;
  __syncthreads();
  for (int off = 128; off > 0; off >>= 1) {
    if (t < off) red[t] += red[t + off];
    __syncthreads();
  }
  if (t == 0) bsum[b] = red[0];
}

__global__ void k_scan_mid(const int* __restrict__ bsum, int* __restrict__ boff,
                           int* __restrict__ rowstart) {
  if (threadIdx.x == 0) {
    int run = 0;
    for (int i = 0; i < SCAN_NB; ++i) { boff[i] = run; run += bsum[i]; }
    rowstart[N_NODES] = run;
  }
}

__global__ __launch_bounds__(256) void k_scan_final(const int* __restrict__ deg,
                                                    const int* __restrict__ boff,
                                                    int* __restrict__ rowstart) {
  __shared__ int ts[256];
  int t = threadIdx.x, b = blockIdx.x;
  int base = b * SCAN_CHUNK + t * 16;
  int v[16];
  int s = 0;
#pragma unroll
  for (int i = 0; i < 16; ++i) {
    int idx = base + i;
    v[i] = (idx < N_NODES) ? deg[idx] : 0;
    s += v[i];
  }
  ts[t] = s;
  __syncthreads();
  for (int off = 1; off < 256; off <<= 1) {
    int add = (t >= off) ? ts[t - off] : 0;
    __syncthreads();
    ts[t] += add;
    __syncthreads();
  }
  int run = boff[b] + ts[t] - s;
#pragma unroll
  for (int i = 0; i < 16; ++i) {
    int idx = base + i;
    if (idx < N_NODES) rowstart[idx] = run;
    run += v[i];
  }
}

__global__ __launch_bounds__(256) void k_fill(const int* __restrict__ src,
                                              const int* __restrict__ dst,
                                              int* __restrict__ cursor,
                                              int* __restrict__ srcSorted) {
  int e = blockIdx.x * 256 + threadIdx.x;
  if (e >= N_EDGES) return;
  int d = dst[e];
  int p = atomicAdd(&cursor[d], 1);
  srcSorted[p] = src[e];
}

// ---------------------------------------------------------------------------
// One-time weight split fp32 -> bf16 (hi, lo). Layout preserved: [mat][j][k]
// mats: 0=W_f, 1=U_f, 2=W_h, 3=U_h
// ---------------------------------------------------------------------------
__global__ __launch_bounds__(256) void k_wsplit(const float* __restrict__ W0,
                                                const float* __restrict__ W1,
                                                const float* __restrict__ W2,
                                                const float* __restrict__ W3,
                                                __bf16* __restrict__ Whi,
                                                __bf16* __restrict__ Wlo) {
  int id = blockIdx.x * 256 + threadIdx.x;  // 65536 total
  int mat = id >> 14, idx = id & 16383;
  const float* W = (mat == 0) ? W0 : (mat == 1) ? W1 : (mat == 2) ? W2 : W3;
  float v = W[idx];
  __bf16 hi = (__bf16)v;
  Whi[id] = hi;
  Wlo[id] = (__bf16)(v - (float)hi);
}

// ---------------------------------------------------------------------------
// Aggregation (gather): m[n] = sum_{j in CSR[n]} h[srcSorted[j]]
// ---------------------------------------------------------------------------
__global__ __launch_bounds__(256) void k_gather(const float* __restrict__ h,
                                                const int* __restrict__ rowstart,
                                                const int* __restrict__ srcSorted,
                                                float* __restrict__ m) {
  int node = blockIdx.x * 4 + (threadIdx.x >> 6);
  if (node >= N_NODES) return;
  int l = threadIdx.x & 63;
  int j0 = rowstart[node], j1 = rowstart[node + 1];
  const float2* h2 = (const float2*)h;
  float2 a0 = {0.f, 0.f}, a1 = {0.f, 0.f};
  int j = j0;
  for (; j + 1 < j1; j += 2) {
    int s0 = srcSorted[j], s1 = srcSorted[j + 1];
    float2 v0 = h2[s0 * 64 + l];
    float2 v1 = h2[s1 * 64 + l];
    a0.x += v0.x; a0.y += v0.y;
    a1.x += v1.x; a1.y += v1.y;
  }
  if (j < j1) {
    int s0 = srcSorted[j];
    float2 v0 = h2[s0 * 64 + l];
    a0.x += v0.x; a0.y += v0.y;
  }
  float2 o = {a0.x + a1.x, a0.y + a1.y};
  ((float2*)m)[node * 64 + l] = o;
}

// ---------------------------------------------------------------------------
// Fused MGU update, MFMA split-bf16 (R4 version, in-place on h).
// ---------------------------------------------------------------------------
__global__ __launch_bounds__(256) void k_mgu(float* __restrict__ h,
                                             const float* __restrict__ m,
                                             const __bf16* __restrict__ Whi,
                                             const __bf16* __restrict__ Wlo,
                                             const float* __restrict__ bfp,
                                             const float* __restrict__ bhp) {
  __shared__ __bf16 mHi[32 * LDST], mLo[32 * LDST];
  __shared__ __bf16 hHi[32 * LDST], hLo[32 * LDST];
  __shared__ __bf16 gHi[32 * LDST], gLo[32 * LDST];
  const int t = threadIdx.x;
  const int nb = blockIdx.x * 32;

#pragma unroll
  for (int i = 0; i < 4; ++i) {
    int idx4 = i * 256 + t;
    int n = idx4 >> 5, kq = idx4 & 31;
    float4 vm = ((const float4*)m)[(nb + n) * 32 + kq];
    float4 vh = ((const float4*)h)[(nb + n) * 32 + kq];
    bf16x4 mh, ml, hh, hl;
    mh[0] = (__bf16)vm.x; ml[0] = (__bf16)(vm.x - (float)mh[0]);
    mh[1] = (__bf16)vm.y; ml[1] = (__bf16)(vm.y - (float)mh[1]);
    mh[2] = (__bf16)vm.z; ml[2] = (__bf16)(vm.z - (float)mh[2]);
    mh[3] = (__bf16)vm.w; ml[3] = (__bf16)(vm.w - (float)mh[3]);
    hh[0] = (__bf16)vh.x; hl[0] = (__bf16)(vh.x - (float)hh[0]);
    hh[1] = (__bf16)vh.y; hl[1] = (__bf16)(vh.y - (float)hh[1]);
    hh[2] = (__bf16)vh.z; hl[2] = (__bf16)(vh.z - (float)hh[2]);
    hh[3] = (__bf16)vh.w; hl[3] = (__bf16)(vh.w - (float)hh[3]);
    int e0 = n * LDST + 4 * kq;
    *(bf16x4*)&mHi[e0] = mh; *(bf16x4*)&mLo[e0] = ml;
    *(bf16x4*)&hHi[e0] = hh; *(bf16x4*)&hLo[e0] = hl;
  }
  __syncthreads();

  const int w = t >> 6, l = t & 63;
  const int lj = l & 15, q = l >> 4;

  float bfj[2], bhj[2];
#pragma unroll
  for (int ct = 0; ct < 2; ++ct) {
    int j = (2 * w + ct) * 16 + lj;
    bfj[ct] = bfp[j];
    bhj[ct] = bhp[j];
  }

  f32x4 acc[2][2] = {};

  // ---- phase A: z_f = m@Wf.T + h@Uf.T ----
#pragma unroll
  for (int kc = 0; kc < 128; kc += 32) {
    bf16x8 amh[2], aml[2], ahh[2], ahl[2];
#pragma unroll
    for (int rt = 0; rt < 2; ++rt) {
      int e0 = (rt * 16 + lj) * LDST + kc + q * 8;
      amh[rt] = *(const bf16x8*)&mHi[e0];
      aml[rt] = *(const bf16x8*)&mLo[e0];
      ahh[rt] = *(const bf16x8*)&hHi[e0];
      ahl[rt] = *(const bf16x8*)&hLo[e0];
    }
    bf16x8 bwh[2], bwl[2], buh[2], bul[2];
#pragma unroll
    for (int ct = 0; ct < 2; ++ct) {
      int off = ((2 * w + ct) * 16 + lj) * 128 + kc + q * 8;
      bwh[ct] = *(const bf16x8*)&Whi[off];
      bwl[ct] = *(const bf16x8*)&Wlo[off];
      buh[ct] = *(const bf16x8*)&Whi[16384 + off];
      bul[ct] = *(const bf16x8*)&Wlo[16384 + off];
    }
#pragma unroll
    for (int rt = 0; rt < 2; ++rt)
#pragma unroll
      for (int ct = 0; ct < 2; ++ct) {
        f32x4 a = acc[rt][ct];
        a = __builtin_amdgcn_mfma_f32_16x16x32_bf16(amh[rt], bwh[ct], a, 0, 0, 0);
        a = __builtin_amdgcn_mfma_f32_16x16x32_bf16(amh[rt], bwl[ct], a, 0, 0, 0);
        a = __builtin_amdgcn_mfma_f32_16x16x32_bf16(aml[rt], bwh[ct], a, 0, 0, 0);
        a = __builtin_amdgcn_mfma_f32_16x16x32_bf16(ahh[rt], buh[ct], a, 0, 0, 0);
        a = __builtin_amdgcn_mfma_f32_16x16x32_bf16(ahh[rt], bul[ct], a, 0, 0, 0);
        a = __builtin_amdgcn_mfma_f32_16x16x32_bf16(ahl[rt], buh[ct], a, 0, 0, 0);
        acc[rt][ct] = a;
      }
  }

  // ---- transition: f = sigmoid(z_f + bf); g = f*h into gS ----
  float fv[2][2][4], hvv[2][2][4];
#pragma unroll
  for (int rt = 0; rt < 2; ++rt)
#pragma unroll
    for (int ct = 0; ct < 2; ++ct) {
      int j = (2 * w + ct) * 16 + lj;
#pragma unroll
      for (int r = 0; r < 4; ++r) {
        int nl = rt * 16 + q * 4 + r;
        float z = acc[rt][ct][r] + bfj[ct];
        float f = 1.f / (1.f + expf(-z));
        int he = nl * LDST + j;
        float hval = (float)hHi[he] + (float)hLo[he];
        float g = f * hval;
        __bf16 ghi = (__bf16)g;
        gHi[he] = ghi;
        gLo[he] = (__bf16)(g - (float)ghi);
        fv[rt][ct][r] = f;
        hvv[rt][ct][r] = hval;
        acc[rt][ct][r] = 0.f;
      }
    }
  __syncthreads();

  // ---- phase B: z_h = m@Wh.T + g@Uh.T ----
#pragma unroll
  for (int kc = 0; kc < 128; kc += 32) {
    bf16x8 amh[2], aml[2], agh[2], agl[2];
#pragma unroll
    for (int rt = 0; rt < 2; ++rt) {
      int e0 = (rt * 16 + lj) * LDST + kc + q * 8;
      amh[rt] = *(const bf16x8*)&mHi[e0];
      aml[rt] = *(const bf16x8*)&mLo[e0];
      agh[rt] = *(const bf16x8*)&gHi[e0];
      agl[rt] = *(const bf16x8*)&gLo[e0];
    }
    bf16x8 bwh[2], bwl[2], buh[2], bul[2];
#pragma unroll
    for (int ct = 0; ct < 2; ++ct) {
      int off = ((2 * w + ct) * 16 + lj) * 128 + kc + q * 8;
      bwh[ct] = *(const bf16x8*)&Whi[2 * 16384 + off];
      bwl[ct] = *(const bf16x8*)&Wlo[2 * 16384 + off];
      buh[ct] = *(const bf16x8*)&Whi[3 * 16384 + off];
      bul[ct] = *(const bf16x8*)&Wlo[3 * 16384 + off];
    }
#pragma unroll
    for (int rt = 0; rt < 2; ++rt)
#pragma unroll
      for (int ct = 0; ct < 2; ++ct) {
        f32x4 a = acc[rt][ct];
        a = __builtin_amdgcn_mfma_f32_16x16x32_bf16(amh[rt], bwh[ct], a, 0, 0, 0);
        a = __builtin_amdgcn_mfma_f32_16x16x32_bf16(amh[rt], bwl[ct], a, 0, 0, 0);
        a = __builtin_amdgcn_mfma_f32_16x16x32_bf16(aml[rt], bwh[ct], a, 0, 0, 0);
        a = __builtin_amdgcn_mfma_f32_16x16x32_bf16(agh[rt], buh[ct], a, 0, 0, 0);
        a = __builtin_amdgcn_mfma_f32_16x16x32_bf16(agh[rt], bul[ct], a, 0, 0, 0);
        a = __builtin_amdgcn_mfma_f32_16x16x32_bf16(agl[rt], buh[ct], a, 0, 0, 0);
        acc[rt][ct] = a;
      }
  }

  // ---- epilogue: h = (1-f)*h + f*tanh(z_h + bh) ----
#pragma unroll
  for (int rt = 0; rt < 2; ++rt)
#pragma unroll
    for (int ct = 0; ct < 2; ++ct) {
      int j = (2 * w + ct) * 16 + lj;
#pragma unroll
      for (int r = 0; r < 4; ++r) {
        float T = tanhf(acc[rt][ct][r] + bhj[ct]);
        float f = fv[rt][ct][r];
        float hn = (1.f - f) * hvv[rt][ct][r] + f * T;
        h[(nb + rt * 16 + q * 4 + r) * 128 + j] = hn;
      }
    }
}

// ---------------------------------------------------------------------------
// Whole Set2Set in ONE kernel: one block per graph, 1024 threads (16 waves).
// q_star/h_l/c_l/gates live in LDS across all 3 steps; prediction fused.
// ---------------------------------------------------------------------------
__global__ __launch_bounds__(1024) void k_s2s(const float* __restrict__ h,
                                              const int* __restrict__ batch,
                                              const float* __restrict__ w_ih,
                                              const float* __restrict__ w_hh,
                                              const float* __restrict__ b_ih,
                                              const float* __restrict__ b_hh,
                                              const float* __restrict__ Wp,
                                              const float* __restrict__ bp,
                                              float* __restrict__ e,
                                              float* __restrict__ out) {
  const int g = blockIdx.x, t = threadIdx.x;
  const int w = t >> 6, l = t & 63;
  __shared__ float qs[256];          // q_star = [q | r]
  __shared__ float hl[128], cl[128];
  __shared__ float gates[512];
  __shared__ float redM[16], redS[16];
  __shared__ float rPart[16][128];
  __shared__ float gMs, gInvs;
  __shared__ int bnd[2];

  if (t < 2) {
    int tgt = g + t;  // t=0: start of g, t=1: start of g+1
    int lo = 0, hi = N_NODES;
    while (lo < hi) { int mid = (lo + hi) >> 1; if (batch[mid] < tgt) lo = mid + 1; else hi = mid; }
    bnd[t] = lo;
  }
  if (t < 256) qs[t] = 0.f;
  if (t < 128) { hl[t] = 0.f; cl[t] = 0.f; }
  __syncthreads();
  const int s0 = bnd[0], s1 = bnd[1];

  for (int step = 0; step < 3; ++step) {
    // ---- LSTM gates: [512] = q_star@w_ih.T + h_l@w_hh.T + biases ----
    for (int jt = w; jt < 512; jt += 16) {
      const float* wi = w_ih + jt * 256;
      const float* wh = w_hh + jt * 128;
      float s = qs[l] * wi[l] + qs[l+64] * wi[l+64]
              + qs[l+128] * wi[l+128] + qs[l+192] * wi[l+192]
              + hl[l] * wh[l] + hl[l+64] * wh[l+64];
#pragma unroll
      for (int o = 32; o > 0; o >>= 1) s += __shfl_xor(s, o, 64);
      if (l == 0) gates[jt] = s + b_ih[jt] + b_hh[jt];
    }
    __syncthreads();
    if (t < 128) {
      float gi = gates[t], gf = gates[128 + t], gg = gates[256 + t], go = gates[384 + t];
      float c = 1.f/(1.f+expf(-gf)) * cl[t] + 1.f/(1.f+expf(-gi)) * tanhf(gg);
      float hh = 1.f/(1.f+expf(-go)) * tanhf(c);
      cl[t] = c;
      hl[t] = hh;
      qs[t] = hh;  // q part
    }
    __syncthreads();

    // ---- attention pass 1: e[n] = <h[n], q>, online max/sum ----
    float mx = -INFINITY, sm = 0.f;
    for (int n = s0 + w; n < s1; n += 16) {
      float v = h[n*128 + l] * qs[l] + h[n*128 + 64 + l] * qs[64 + l];
#pragma unroll
      for (int o = 32; o > 0; o >>= 1) v += __shfl_xor(v, o, 64);
      if (l == 0) e[n] = v;
      float nm = fmaxf(mx, v);
      sm = sm * expf(mx - nm) + expf(v - nm);
      mx = nm;
    }
    if (l == 0) { redM[w] = mx; redS[w] = sm; }
    __syncthreads();
    if (t == 0) {
      float M = -INFINITY;
      for (int i = 0; i < 16; ++i) M = fmaxf(M, redM[i]);
      float S = 0.f;
      for (int i = 0; i < 16; ++i) if (redS[i] > 0.f) S += redS[i] * expf(redM[i] - M);
      gMs = M; gInvs = (S > 0.f) ? 1.f / S : 0.f;
    }
    __syncthreads();
    const float M = gMs, inv = gInvs;

    // ---- attention pass 2: r = sum softmax * h[n] ----
    float2 acc = {0.f, 0.f};
    const float2* h2 = (const float2*)h;
    for (int n = s0 + w; n < s1; n += 16) {
      float aw = expf(e[n] - M) * inv;
      float2 v = h2[n * 64 + l];
      acc.x += aw * v.x; acc.y += aw * v.y;
    }
    *(float2*)&rPart[w][2 * l] = acc;
    __syncthreads();
    if (t < 128) {
      float r = 0.f;
#pragma unroll
      for (int i = 0; i < 16; ++i) r += rPart[i][t];
      qs[128 + t] = r;
    }
    __syncthreads();
  }

  // ---- prediction: out[g] = <q_star, W_pred> + b ----
  __shared__ float pr[256];
  if (t < 256) pr[t] = qs[t] * Wp[t];
  __syncthreads();
  if (t < 128) pr[t] += pr[t + 128];
  __syncthreads();
  if (t < 64) {
    float s = pr[t] + pr[t + 64];
#pragma unroll
    for (int o = 32; o > 0; o >>= 1) s += __shfl_xor(s, o, 64);
    if (t == 0) out[g] = s + bp[0];
  }
}

// ---------------------------------------------------------------------------
extern "C" void kernel_launch(void* const* d_in, const int* in_sizes, int n_in,
                              void* d_out, int out_size, void* d_ws, size_t ws_size,
                              hipStream_t stream) {
  const float* x      = (const float*)d_in[0];
  const int*   ei     = (const int*)d_in[1];
  const int*   batch  = (const int*)d_in[2];
  const float* W_in   = (const float*)d_in[3];
  const float* b_in   = (const float*)d_in[4];
  const float* W_f    = (const float*)d_in[5];
  const float* U_f    = (const float*)d_in[6];
  const float* b_f    = (const float*)d_in[7];
  const float* W_h    = (const float*)d_in[8];
  const float* U_h    = (const float*)d_in[9];
  const float* b_h    = (const float*)d_in[10];
  const float* w_ih   = (const float*)d_in[11];
  const float* w_hh   = (const float*)d_in[12];
  const float* b_ih   = (const float*)d_in[13];
  const float* b_hh   = (const float*)d_in[14];
  const float* W_pred = (const float*)d_in[15];
  const float* b_pred = (const float*)d_in[16];
  float* out = (float*)d_out;

  char* ws = (char*)d_ws;
  float* h      = (float*)(ws);                    // 51,200,000 B
  float* m      = (float*)(ws + 51200000);         // 51,200,000 B
  float* e      = (float*)(ws + 102400000);        //    400,000 B (aliased below)
  int*   rowstart = (int*)(ws + 103063808);        //    400,016 B
  int*   srcSorted= (int*)(ws + 103463824);        //  2,560,000 B
  int*   bsum   = (int*)  (ws + 106023824);        //        112 B
  int*   boff   = (int*)  (ws + 106023936);        //        112 B
  // 'e' region lifetimes: deg/cursor (CSR build) -> Whi/Wlo (MPNN loop,
  // 262,144 B <= 400,000) -> e attention scores (set2set)
  int*    deg    = (int*)e;
  int*    cursor = (int*)e;
  __bf16* Whi    = (__bf16*)(ws + 102400000);      //    131,072 B
  __bf16* Wlo    = (__bf16*)(ws + 102531072);      //    131,072 B

  const int* src = ei;
  const int* dst = ei + N_EDGES;

  // ---- CSR build (once; reused by all 3 MPNN steps) ----
  hipMemsetAsync(deg, 0, N_NODES * 4, stream);
  k_hist<<<(N_EDGES + 255) / 256, 256, 0, stream>>>(dst, deg);
  k_scan_part<<<SCAN_NB, 256, 0, stream>>>(deg, bsum);
  k_scan_mid<<<1, 32, 0, stream>>>(bsum, boff, rowstart);
  k_scan_final<<<SCAN_NB, 256, 0, stream>>>(deg, boff, rowstart);
  hipMemcpyAsync(cursor, rowstart, N_NODES * 4, hipMemcpyDeviceToDevice, stream);
  k_fill<<<(N_EDGES + 255) / 256, 256, 0, stream>>>(src, dst, cursor, srcSorted);

  // ---- one-time weight bf16 hi/lo split (overwrites deg/cursor region) ----
  k_wsplit<<<256, 256, 0, stream>>>(W_f, U_f, W_h, U_h, Whi, Wlo);

  k_input<<<N_NODES / 32, 256, 0, stream>>>(x, W_in, b_in, h);

  for (int step = 0; step < 3; ++step) {
    k_gather<<<(N_NODES + 3) / 4, 256, 0, stream>>>(h, rowstart, srcSorted, m);
    k_mgu<<<N_NODES / 32, 256, 0, stream>>>(h, m, Whi, Wlo, b_f, b_h);
  }

  // ---- entire Set2Set + prediction in one launch ----
  k_s2s<<<NGRAPH, 1024, 0, stream>>>(h, batch, w_ih, w_hh, b_ih, b_hh,
                                     W_pred, b_pred, e, out);
}

// Round 7
// 824.002 us; speedup vs baseline: 2.1236x; 1.1986x over previous
//
#include <hip/hip_runtime.h>
#include <math.h>

#define N_NODES 100000
#define N_EDGES 640000
#define IN_DIM 64
#define HID 128
#define NGRAPH 128

typedef __bf16 bf16x2 __attribute__((ext_vector_type(2)));
typedef __bf16 bf16x4 __attribute__((ext_vector_type(4)));
typedef __bf16 bf16x8 __attribute__((ext_vector_type(8)));
typedef float f32x4 __attribute__((ext_vector_type(4)));

#define LDST 136  // bf16 elements per LDS row: 272 B, 16B-aligned, breaks pow2 stride

// ---------------------------------------------------------------------------
// fma helper (used by k_input only)
// ---------------------------------------------------------------------------
__device__ __forceinline__ void fma44(const float4 A[4], const float4 B[4], float acc[4][4]) {
#pragma unroll
  for (int i2 = 0; i2 < 4; ++i2) {
    acc[i2][0] += A[i2].x*B[0].x + A[i2].y*B[1].x + A[i2].z*B[2].x + A[i2].w*B[3].x;
    acc[i2][1] += A[i2].x*B[0].y + A[i2].y*B[1].y + A[i2].z*B[2].y + A[i2].w*B[3].y;
    acc[i2][2] += A[i2].x*B[0].z + A[i2].y*B[1].z + A[i2].z*B[2].z + A[i2].w*B[3].z;
    acc[i2][3] += A[i2].x*B[0].w + A[i2].y*B[1].w + A[i2].z*B[2].w + A[i2].w*B[3].w;
  }
}

// ---------------------------------------------------------------------------
// Kernel 1: h = relu(x @ W_in.T + b_in)
// ---------------------------------------------------------------------------
__global__ __launch_bounds__(256) void k_input(const float* __restrict__ x,
                                               const float* __restrict__ W,
                                               const float* __restrict__ b,
                                               float* __restrict__ h) {
  __shared__ float wS[64][132];
  __shared__ float xS[32][68];
  int t = threadIdx.x;
  int nb = blockIdx.x * 32;
#pragma unroll
  for (int i = 0; i < 8; ++i) {
    int idx4 = i * 256 + t;
    int j = idx4 >> 4, kq = idx4 & 15;
    float4 v = ((const float4*)W)[j * 16 + kq];
    wS[4*kq+0][j] = v.x; wS[4*kq+1][j] = v.y; wS[4*kq+2][j] = v.z; wS[4*kq+3][j] = v.w;
  }
#pragma unroll
  for (int i = 0; i < 2; ++i) {
    int idx4 = i * 256 + t;
    int n = idx4 >> 4, kq = idx4 & 15;
    float4 v = ((const float4*)x)[(nb + n) * 16 + kq];
    *((float4*)&xS[n][4*kq]) = v;
  }
  __syncthreads();
  int bq = t & 31, a = t >> 5;
  float acc[4][4] = {};
#pragma unroll
  for (int kk4 = 0; kk4 < 16; ++kk4) {
    float4 A[4], B[4];
#pragma unroll
    for (int i2 = 0; i2 < 4; ++i2) A[i2] = *((const float4*)&xS[4*a+i2][4*kk4]);
#pragma unroll
    for (int c = 0; c < 4; ++c) B[c] = *((const float4*)&wS[4*kk4+c][4*bq]);
    fma44(A, B, acc);
  }
  float4 bb = ((const float4*)b)[bq];
  float ba[4] = {bb.x, bb.y, bb.z, bb.w};
#pragma unroll
  for (int i2 = 0; i2 < 4; ++i2) {
    float4 o;
    o.x = fmaxf(acc[i2][0] + ba[0], 0.f);
    o.y = fmaxf(acc[i2][1] + ba[1], 0.f);
    o.z = fmaxf(acc[i2][2] + ba[2], 0.f);
    o.w = fmaxf(acc[i2][3] + ba[3], 0.f);
    ((float4*)h)[(nb + 4*a + i2) * 32 + bq] = o;
  }
}

// ---------------------------------------------------------------------------
// CSR build: histogram -> scan -> fill
// ---------------------------------------------------------------------------
__global__ __launch_bounds__(256) void k_hist(const int* __restrict__ dst,
                                              int* __restrict__ deg) {
  int e = blockIdx.x * 256 + threadIdx.x;
  if (e < N_EDGES) atomicAdd(&deg[dst[e]], 1);
}

#define SCAN_CHUNK 4096
#define SCAN_NB 25

__global__ __launch_bounds__(256) void k_scan_part(const int* __restrict__ deg,
                                                   int* __restrict__ bsum) {
  __shared__ int red[256];
  int t = threadIdx.x, b = blockIdx.x;
  int base = b * SCAN_CHUNK + t * 16;
  int s = 0;
#pragma unroll
  for (int i = 0; i < 16; ++i) {
    int idx = base + i;
    if (idx < N_NODES) s += deg[idx];
  }
  red[t] = s;
  __syncthreads();
  for (int off = 128; off > 0; off >>= 1) {
    if (t < off) red[t] += red[t + off];
    __syncthreads();
  }
  if (t == 0) bsum[b] = red[0];
}

__global__ void k_scan_mid(const int* __restrict__ bsum, int* __restrict__ boff,
                           int* __restrict__ rowstart) {
  if (threadIdx.x == 0) {
    int run = 0;
    for (int i = 0; i < SCAN_NB; ++i) { boff[i] = run; run += bsum[i]; }
    rowstart[N_NODES] = run;
  }
}

__global__ __launch_bounds__(256) void k_scan_final(const int* __restrict__ deg,
                                                    const int* __restrict__ boff,
                                                    int* __restrict__ rowstart) {
  __shared__ int ts[256];
  int t = threadIdx.x, b = blockIdx.x;
  int base = b * SCAN_CHUNK + t * 16;
  int v[16];
  int s = 0;
#pragma unroll
  for (int i = 0; i < 16; ++i) {
    int idx = base + i;
    v[i] = (idx < N_NODES) ? deg[idx] : 0;
    s += v[i];
  }
  ts[t] = s;
  __syncthreads();
  for (int off = 1; off < 256; off <<= 1) {
    int add = (t >= off) ? ts[t - off] : 0;
    __syncthreads();
    ts[t] += add;
    __syncthreads();
  }
  int run = boff[b] + ts[t] - s;
#pragma unroll
  for (int i = 0; i < 16; ++i) {
    int idx = base + i;
    if (idx < N_NODES) rowstart[idx] = run;
    run += v[i];
  }
}

__global__ __launch_bounds__(256) void k_fill(const int* __restrict__ src,
                                              const int* __restrict__ dst,
                                              int* __restrict__ cursor,
                                              int* __restrict__ srcSorted) {
  int e = blockIdx.x * 256 + threadIdx.x;
  if (e >= N_EDGES) return;
  int d = dst[e];
  int p = atomicAdd(&cursor[d], 1);
  srcSorted[p] = src[e];
}

// ---------------------------------------------------------------------------
// One-time weight split fp32 -> bf16 (hi, lo). Layout preserved: [mat][j][k]
// ---------------------------------------------------------------------------
__global__ __launch_bounds__(256) void k_wsplit(const float* __restrict__ W0,
                                                const float* __restrict__ W1,
                                                const float* __restrict__ W2,
                                                const float* __restrict__ W3,
                                                __bf16* __restrict__ Whi,
                                                __bf16* __restrict__ Wlo) {
  int id = blockIdx.x * 256 + threadIdx.x;  // 65536 total
  int mat = id >> 14, idx = id & 16383;
  const float* W = (mat == 0) ? W0 : (mat == 1) ? W1 : (mat == 2) ? W2 : W3;
  float v = W[idx];
  __bf16 hi = (__bf16)v;
  Whi[id] = hi;
  Wlo[id] = (__bf16)(v - (float)hi);
}

// ---------------------------------------------------------------------------
// Aggregation (gather): m[n] = sum_{j in CSR[n]} h[srcSorted[j]]
// ---------------------------------------------------------------------------
__global__ __launch_bounds__(256) void k_gather(const float* __restrict__ h,
                                                const int* __restrict__ rowstart,
                                                const int* __restrict__ srcSorted,
                                                float* __restrict__ m) {
  int node = blockIdx.x * 4 + (threadIdx.x >> 6);
  if (node >= N_NODES) return;
  int l = threadIdx.x & 63;
  int j0 = rowstart[node], j1 = rowstart[node + 1];
  const float2* h2 = (const float2*)h;
  float2 a0 = {0.f, 0.f}, a1 = {0.f, 0.f};
  int j = j0;
  for (; j + 1 < j1; j += 2) {
    int s0 = srcSorted[j], s1 = srcSorted[j + 1];
    float2 v0 = h2[s0 * 64 + l];
    float2 v1 = h2[s1 * 64 + l];
    a0.x += v0.x; a0.y += v0.y;
    a1.x += v1.x; a1.y += v1.y;
  }
  if (j < j1) {
    int s0 = srcSorted[j];
    float2 v0 = h2[s0 * 64 + l];
    a0.x += v0.x; a0.y += v0.y;
  }
  float2 o = {a0.x + a1.x, a0.y + a1.y};
  ((float2*)m)[node * 64 + l] = o;
}

// ---------------------------------------------------------------------------
// Fused MGU update, MFMA split-bf16, in-place on h.
// v3: g = f*h overwrites the h tile (no gS) -> LDS 34,816 B -> 4 blocks/CU.
// ---------------------------------------------------------------------------
__global__ __launch_bounds__(256) void k_mgu(float* __restrict__ h,
                                             const float* __restrict__ m,
                                             const __bf16* __restrict__ Whi,
                                             const __bf16* __restrict__ Wlo,
                                             const float* __restrict__ bfp,
                                             const float* __restrict__ bhp) {
  __shared__ __bf16 mHi[32 * LDST], mLo[32 * LDST];
  __shared__ __bf16 hHi[32 * LDST], hLo[32 * LDST];  // becomes g after f-gate
  const int t = threadIdx.x;
  const int nb = blockIdx.x * 32;

#pragma unroll
  for (int i = 0; i < 4; ++i) {
    int idx4 = i * 256 + t;
    int n = idx4 >> 5, kq = idx4 & 31;
    float4 vm = ((const float4*)m)[(nb + n) * 32 + kq];
    float4 vh = ((const float4*)h)[(nb + n) * 32 + kq];
    bf16x4 mh, ml, hh, hl;
    mh[0] = (__bf16)vm.x; ml[0] = (__bf16)(vm.x - (float)mh[0]);
    mh[1] = (__bf16)vm.y; ml[1] = (__bf16)(vm.y - (float)mh[1]);
    mh[2] = (__bf16)vm.z; ml[2] = (__bf16)(vm.z - (float)mh[2]);
    mh[3] = (__bf16)vm.w; ml[3] = (__bf16)(vm.w - (float)mh[3]);
    hh[0] = (__bf16)vh.x; hl[0] = (__bf16)(vh.x - (float)hh[0]);
    hh[1] = (__bf16)vh.y; hl[1] = (__bf16)(vh.y - (float)hh[1]);
    hh[2] = (__bf16)vh.z; hl[2] = (__bf16)(vh.z - (float)hh[2]);
    hh[3] = (__bf16)vh.w; hl[3] = (__bf16)(vh.w - (float)hh[3]);
    int e0 = n * LDST + 4 * kq;
    *(bf16x4*)&mHi[e0] = mh; *(bf16x4*)&mLo[e0] = ml;
    *(bf16x4*)&hHi[e0] = hh; *(bf16x4*)&hLo[e0] = hl;
  }
  __syncthreads();

  const int w = t >> 6, l = t & 63;
  const int lj = l & 15, q = l >> 4;

  float bfj[2], bhj[2];
#pragma unroll
  for (int ct = 0; ct < 2; ++ct) {
    int j = (2 * w + ct) * 16 + lj;
    bfj[ct] = bfp[j];
    bhj[ct] = bhp[j];
  }

  f32x4 acc[2][2] = {};

  // ---- phase A: z_f = m@Wf.T + h@Uf.T ----
#pragma unroll
  for (int kc = 0; kc < 128; kc += 32) {
    bf16x8 amh[2], aml[2], ahh[2], ahl[2];
#pragma unroll
    for (int rt = 0; rt < 2; ++rt) {
      int e0 = (rt * 16 + lj) * LDST + kc + q * 8;
      amh[rt] = *(const bf16x8*)&mHi[e0];
      aml[rt] = *(const bf16x8*)&mLo[e0];
      ahh[rt] = *(const bf16x8*)&hHi[e0];
      ahl[rt] = *(const bf16x8*)&hLo[e0];
    }
    bf16x8 bwh[2], bwl[2], buh[2], bul[2];
#pragma unroll
    for (int ct = 0; ct < 2; ++ct) {
      int off = ((2 * w + ct) * 16 + lj) * 128 + kc + q * 8;
      bwh[ct] = *(const bf16x8*)&Whi[off];
      bwl[ct] = *(const bf16x8*)&Wlo[off];
      buh[ct] = *(const bf16x8*)&Whi[16384 + off];
      bul[ct] = *(const bf16x8*)&Wlo[16384 + off];
    }
#pragma unroll
    for (int rt = 0; rt < 2; ++rt)
#pragma unroll
      for (int ct = 0; ct < 2; ++ct) {
        f32x4 a = acc[rt][ct];
        a = __builtin_amdgcn_mfma_f32_16x16x32_bf16(amh[rt], bwh[ct], a, 0, 0, 0);
        a = __builtin_amdgcn_mfma_f32_16x16x32_bf16(amh[rt], bwl[ct], a, 0, 0, 0);
        a = __builtin_amdgcn_mfma_f32_16x16x32_bf16(aml[rt], bwh[ct], a, 0, 0, 0);
        a = __builtin_amdgcn_mfma_f32_16x16x32_bf16(ahh[rt], buh[ct], a, 0, 0, 0);
        a = __builtin_amdgcn_mfma_f32_16x16x32_bf16(ahh[rt], bul[ct], a, 0, 0, 0);
        a = __builtin_amdgcn_mfma_f32_16x16x32_bf16(ahl[rt], buh[ct], a, 0, 0, 0);
        acc[rt][ct] = a;
      }
  }

  // ---- transition: f = sigmoid(z_f + bf); g = f*h overwrites h tile ----
  __syncthreads();  // all phase-A reads of hHi/hLo complete
  float fv[2][2][4], hvv[2][2][4];
#pragma unroll
  for (int rt = 0; rt < 2; ++rt)
#pragma unroll
    for (int ct = 0; ct < 2; ++ct) {
      int j = (2 * w + ct) * 16 + lj;
#pragma unroll
      for (int r = 0; r < 4; ++r) {
        int nl = rt * 16 + q * 4 + r;
        float z = acc[rt][ct][r] + bfj[ct];
        float f = 1.f / (1.f + expf(-z));
        int he = nl * LDST + j;
        float hval = (float)hHi[he] + (float)hLo[he];
        float g = f * hval;
        __bf16 ghi = (__bf16)g;
        hHi[he] = ghi;
        hLo[he] = (__bf16)(g - (float)ghi);
        fv[rt][ct][r] = f;
        hvv[rt][ct][r] = hval;
        acc[rt][ct][r] = 0.f;
      }
    }
  __syncthreads();

  // ---- phase B: z_h = m@Wh.T + g@Uh.T ----
#pragma unroll
  for (int kc = 0; kc < 128; kc += 32) {
    bf16x8 amh[2], aml[2], agh[2], agl[2];
#pragma unroll
    for (int rt = 0; rt < 2; ++rt) {
      int e0 = (rt * 16 + lj) * LDST + kc + q * 8;
      amh[rt] = *(const bf16x8*)&mHi[e0];
      aml[rt] = *(const bf16x8*)&mLo[e0];
      agh[rt] = *(const bf16x8*)&hHi[e0];
      agl[rt] = *(const bf16x8*)&hLo[e0];
    }
    bf16x8 bwh[2], bwl[2], buh[2], bul[2];
#pragma unroll
    for (int ct = 0; ct < 2; ++ct) {
      int off = ((2 * w + ct) * 16 + lj) * 128 + kc + q * 8;
      bwh[ct] = *(const bf16x8*)&Whi[2 * 16384 + off];
      bwl[ct] = *(const bf16x8*)&Wlo[2 * 16384 + off];
      buh[ct] = *(const bf16x8*)&Whi[3 * 16384 + off];
      bul[ct] = *(const bf16x8*)&Wlo[3 * 16384 + off];
    }
#pragma unroll
    for (int rt = 0; rt < 2; ++rt)
#pragma unroll
      for (int ct = 0; ct < 2; ++ct) {
        f32x4 a = acc[rt][ct];
        a = __builtin_amdgcn_mfma_f32_16x16x32_bf16(amh[rt], bwh[ct], a, 0, 0, 0);
        a = __builtin_amdgcn_mfma_f32_16x16x32_bf16(amh[rt], bwl[ct], a, 0, 0, 0);
        a = __builtin_amdgcn_mfma_f32_16x16x32_bf16(aml[rt], bwh[ct], a, 0, 0, 0);
        a = __builtin_amdgcn_mfma_f32_16x16x32_bf16(agh[rt], buh[ct], a, 0, 0, 0);
        a = __builtin_amdgcn_mfma_f32_16x16x32_bf16(agh[rt], bul[ct], a, 0, 0, 0);
        a = __builtin_amdgcn_mfma_f32_16x16x32_bf16(agl[rt], buh[ct], a, 0, 0, 0);
        acc[rt][ct] = a;
      }
  }

  // ---- epilogue: h = (1-f)*h + f*tanh(z_h + bh) ----
#pragma unroll
  for (int rt = 0; rt < 2; ++rt)
#pragma unroll
    for (int ct = 0; ct < 2; ++ct) {
      int j = (2 * w + ct) * 16 + lj;
#pragma unroll
      for (int r = 0; r < 4; ++r) {
        float T = tanhf(acc[rt][ct][r] + bhj[ct]);
        float f = fv[rt][ct][r];
        float hn = (1.f - f) * hvv[rt][ct][r] + f * T;
        h[(nb + rt * 16 + q * 4 + r) * 128 + j] = hn;
      }
    }
}

// ---------------------------------------------------------------------------
// Whole Set2Set in ONE kernel, flash-style fused attention (single pass over
// h per step, no e round-trip). One block/graph, 1024 threads = 16 waves =
// 32 half-wave streams; each half-wave (32 lanes x float4) processes one node
// per iteration with a 5-shuffle reduce.
// ---------------------------------------------------------------------------
__global__ __launch_bounds__(1024) void k_s2s(const float* __restrict__ h,
                                              const int* __restrict__ batch,
                                              const float* __restrict__ w_ih,
                                              const float* __restrict__ w_hh,
                                              const float* __restrict__ b_ih,
                                              const float* __restrict__ b_hh,
                                              const float* __restrict__ Wp,
                                              const float* __restrict__ bp,
                                              float* __restrict__ out) {
  const int g = blockIdx.x, t = threadIdx.x;
  const int w = t >> 6, l = t & 63;
  const int half = l >> 5, li = l & 31;
  const int hw = 2 * w + half;           // stream id 0..31
  __shared__ float qs[256];              // q_star = [q | r]
  __shared__ float hl[128], cl[128];
  __shared__ float gates[512];
  __shared__ float redM[32], redS[32], scl[32];
  __shared__ float rPart[32][132];       // row stride 528 B (16B aligned)
  __shared__ float gInvS;
  __shared__ int bnd[2];

  if (t < 2) {
    int tgt = g + t;
    int lo = 0, hi = N_NODES;
    while (lo < hi) { int mid = (lo + hi) >> 1; if (batch[mid] < tgt) lo = mid + 1; else hi = mid; }
    bnd[t] = lo;
  }
  if (t < 256) qs[t] = 0.f;
  if (t < 128) { hl[t] = 0.f; cl[t] = 0.f; }
  __syncthreads();
  const int s0 = bnd[0], s1 = bnd[1];

  for (int step = 0; step < 3; ++step) {
    // ---- LSTM gates: [512] = q_star@w_ih.T + h_l@w_hh.T + biases ----
    for (int jt = w; jt < 512; jt += 16) {
      const float* wi = w_ih + jt * 256;
      const float* wh = w_hh + jt * 128;
      float s = qs[l] * wi[l] + qs[l+64] * wi[l+64]
              + qs[l+128] * wi[l+128] + qs[l+192] * wi[l+192]
              + hl[l] * wh[l] + hl[l+64] * wh[l+64];
#pragma unroll
      for (int o = 32; o > 0; o >>= 1) s += __shfl_xor(s, o, 64);
      if (l == 0) gates[jt] = s + b_ih[jt] + b_hh[jt];
    }
    __syncthreads();
    if (t < 128) {
      float gi = gates[t], gf = gates[128 + t], gg = gates[256 + t], go = gates[384 + t];
      float c = 1.f/(1.f+expf(-gf)) * cl[t] + 1.f/(1.f+expf(-gi)) * tanhf(gg);
      float hh = 1.f/(1.f+expf(-go)) * tanhf(c);
      cl[t] = c;
      hl[t] = hh;
      qs[t] = hh;  // q part
    }
    __syncthreads();

    // ---- fused attention (online softmax, single pass over h) ----
    float mw = -INFINITY, sw = 0.f;
    float4 racc = {0.f, 0.f, 0.f, 0.f};
    const float4* h4 = (const float4*)h;
    const float q0 = qs[4*li], q1 = qs[4*li+1], q2 = qs[4*li+2], q3 = qs[4*li+3];
    for (int n = s0 + hw; n < s1; n += 32) {
      float4 hv = h4[n * 32 + li];
      float v = hv.x * q0 + hv.y * q1 + hv.z * q2 + hv.w * q3;
#pragma unroll
      for (int o = 16; o > 0; o >>= 1) v += __shfl_xor(v, o, 64);  // within half
      float nm = fmaxf(mw, v);
      float sc = expf(mw - nm);
      float wg = expf(v - nm);
      sw = sw * sc + wg;
      racc.x = racc.x * sc + wg * hv.x;
      racc.y = racc.y * sc + wg * hv.y;
      racc.z = racc.z * sc + wg * hv.z;
      racc.w = racc.w * sc + wg * hv.w;
      mw = nm;
    }
    if (li == 0) { redM[hw] = mw; redS[hw] = sw; }
    *(float4*)&rPart[hw][4 * li] = racc;
    __syncthreads();
    if (t == 0) {
      float M = -INFINITY;
      for (int i = 0; i < 32; ++i) M = fmaxf(M, redM[i]);
      float S = 0.f;
      for (int i = 0; i < 32; ++i) {
        float s_ = (redM[i] > -INFINITY && M > -INFINITY) ? expf(redM[i] - M) : 0.f;
        scl[i] = s_;
        S += redS[i] * s_;
      }
      gInvS = (S > 0.f) ? 1.f / S : 0.f;
    }
    __syncthreads();
    if (t < 128) {
      float inv = gInvS;
      float r = 0.f;
#pragma unroll
      for (int i = 0; i < 32; ++i) r += rPart[i][t] * scl[i];
      qs[128 + t] = r * inv;
    }
    __syncthreads();
  }

  // ---- prediction: out[g] = <q_star, W_pred> + b ----
  __shared__ float pr[256];
  if (t < 256) pr[t] = qs[t] * Wp[t];
  __syncthreads();
  if (t < 128) pr[t] += pr[t + 128];
  __syncthreads();
  if (t < 64) {
    float s = pr[t] + pr[t + 64];
#pragma unroll
    for (int o = 32; o > 0; o >>= 1) s += __shfl_xor(s, o, 64);
    if (t == 0) out[g] = s + bp[0];
  }
}

// ---------------------------------------------------------------------------
extern "C" void kernel_launch(void* const* d_in, const int* in_sizes, int n_in,
                              void* d_out, int out_size, void* d_ws, size_t ws_size,
                              hipStream_t stream) {
  const float* x      = (const float*)d_in[0];
  const int*   ei     = (const int*)d_in[1];
  const int*   batch  = (const int*)d_in[2];
  const float* W_in   = (const float*)d_in[3];
  const float* b_in   = (const float*)d_in[4];
  const float* W_f    = (const float*)d_in[5];
  const float* U_f    = (const float*)d_in[6];
  const float* b_f    = (const float*)d_in[7];
  const float* W_h    = (const float*)d_in[8];
  const float* U_h    = (const float*)d_in[9];
  const float* b_h    = (const float*)d_in[10];
  const float* w_ih   = (const float*)d_in[11];
  const float* w_hh   = (const float*)d_in[12];
  const float* b_ih   = (const float*)d_in[13];
  const float* b_hh   = (const float*)d_in[14];
  const float* W_pred = (const float*)d_in[15];
  const float* b_pred = (const float*)d_in[16];
  float* out = (float*)d_out;

  char* ws = (char*)d_ws;
  float* h      = (float*)(ws);                    // 51,200,000 B
  float* m      = (float*)(ws + 51200000);         // 51,200,000 B
  int*   rowstart = (int*)(ws + 103063808);        //    400,016 B
  int*   srcSorted= (int*)(ws + 103463824);        //  2,560,000 B
  int*   bsum   = (int*)  (ws + 106023824);        //        112 B
  int*   boff   = (int*)  (ws + 106023936);        //        112 B
  // region at +102,400,000 (400,000 B): deg/cursor (CSR build) then Whi/Wlo
  int*    deg    = (int*)(ws + 102400000);
  int*    cursor = (int*)(ws + 102400000);
  __bf16* Whi    = (__bf16*)(ws + 102400000);      //    131,072 B
  __bf16* Wlo    = (__bf16*)(ws + 102531072);      //    131,072 B

  const int* src = ei;
  const int* dst = ei + N_EDGES;

  // ---- CSR build (once; reused by all 3 MPNN steps) ----
  hipMemsetAsync(deg, 0, N_NODES * 4, stream);
  k_hist<<<(N_EDGES + 255) / 256, 256, 0, stream>>>(dst, deg);
  k_scan_part<<<SCAN_NB, 256, 0, stream>>>(deg, bsum);
  k_scan_mid<<<1, 32, 0, stream>>>(bsum, boff, rowstart);
  k_scan_final<<<SCAN_NB, 256, 0, stream>>>(deg, boff, rowstart);
  hipMemcpyAsync(cursor, rowstart, N_NODES * 4, hipMemcpyDeviceToDevice, stream);
  k_fill<<<(N_EDGES + 255) / 256, 256, 0, stream>>>(src, dst, cursor, srcSorted);

  // ---- one-time weight bf16 hi/lo split (overwrites deg/cursor region) ----
  k_wsplit<<<256, 256, 0, stream>>>(W_f, U_f, W_h, U_h, Whi, Wlo);

  k_input<<<N_NODES / 32, 256, 0, stream>>>(x, W_in, b_in, h);

  for (int step = 0; step < 3; ++step) {
    k_gather<<<(N_NODES + 3) / 4, 256, 0, stream>>>(h, rowstart, srcSorted, m);
    k_mgu<<<N_NODES / 32, 256, 0, stream>>>(h, m, Whi, Wlo, b_f, b_h);
  }

  // ---- entire Set2Set + prediction in one launch ----
  k_s2s<<<NGRAPH, 1024, 0, stream>>>(h, batch, w_ih, w_hh, b_ih, b_hh,
                                     W_pred, b_pred, out);
}

// Round 8
// 793.591 us; speedup vs baseline: 2.2049x; 1.0383x over previous
//
#include <hip/hip_runtime.h>
#include <math.h>

#define N_NODES 100000
#define N_EDGES 640000
#define IN_DIM 64
#define HID 128
#define NGRAPH 128

typedef __bf16 bf16x2 __attribute__((ext_vector_type(2)));
typedef __bf16 bf16x4 __attribute__((ext_vector_type(4)));
typedef __bf16 bf16x8 __attribute__((ext_vector_type(8)));
typedef float f32x4 __attribute__((ext_vector_type(4)));

#define LDST 136  // bf16 elements per LDS row: 272 B, 16B-aligned, breaks pow2 stride

// fast transcendentals: __expf -> v_exp_f32 path, __fdividef -> mul by rcp.
// inf-safe: sigmoid(-inf)=0, sigmoid(inf)=1, tanh(+-inf)=+-1.
__device__ __forceinline__ float sigmoid_f(float z) {
  return __fdividef(1.f, 1.f + __expf(-z));
}
__device__ __forceinline__ float tanh_f(float z) {
  return 1.f - __fdividef(2.f, __expf(2.f * z) + 1.f);
}

// ---------------------------------------------------------------------------
// fma helper (used by k_input only)
// ---------------------------------------------------------------------------
__device__ __forceinline__ void fma44(const float4 A[4], const float4 B[4], float acc[4][4]) {
#pragma unroll
  for (int i2 = 0; i2 < 4; ++i2) {
    acc[i2][0] += A[i2].x*B[0].x + A[i2].y*B[1].x + A[i2].z*B[2].x + A[i2].w*B[3].x;
    acc[i2][1] += A[i2].x*B[0].y + A[i2].y*B[1].y + A[i2].z*B[2].y + A[i2].w*B[3].y;
    acc[i2][2] += A[i2].x*B[0].z + A[i2].y*B[1].z + A[i2].z*B[2].z + A[i2].w*B[3].z;
    acc[i2][3] += A[i2].x*B[0].w + A[i2].y*B[1].w + A[i2].z*B[2].w + A[i2].w*B[3].w;
  }
}

// ---------------------------------------------------------------------------
// Kernel 1: h = relu(x @ W_in.T + b_in)
// ---------------------------------------------------------------------------
__global__ __launch_bounds__(256) void k_input(const float* __restrict__ x,
                                               const float* __restrict__ W,
                                               const float* __restrict__ b,
                                               float* __restrict__ h) {
  __shared__ float wS[64][132];
  __shared__ float xS[32][68];
  int t = threadIdx.x;
  int nb = blockIdx.x * 32;
#pragma unroll
  for (int i = 0; i < 8; ++i) {
    int idx4 = i * 256 + t;
    int j = idx4 >> 4, kq = idx4 & 15;
    float4 v = ((const float4*)W)[j * 16 + kq];
    wS[4*kq+0][j] = v.x; wS[4*kq+1][j] = v.y; wS[4*kq+2][j] = v.z; wS[4*kq+3][j] = v.w;
  }
#pragma unroll
  for (int i = 0; i < 2; ++i) {
    int idx4 = i * 256 + t;
    int n = idx4 >> 4, kq = idx4 & 15;
    float4 v = ((const float4*)x)[(nb + n) * 16 + kq];
    *((float4*)&xS[n][4*kq]) = v;
  }
  __syncthreads();
  int bq = t & 31, a = t >> 5;
  float acc[4][4] = {};
#pragma unroll
  for (int kk4 = 0; kk4 < 16; ++kk4) {
    float4 A[4], B[4];
#pragma unroll
    for (int i2 = 0; i2 < 4; ++i2) A[i2] = *((const float4*)&xS[4*a+i2][4*kk4]);
#pragma unroll
    for (int c = 0; c < 4; ++c) B[c] = *((const float4*)&wS[4*kk4+c][4*bq]);
    fma44(A, B, acc);
  }
  float4 bb = ((const float4*)b)[bq];
  float ba[4] = {bb.x, bb.y, bb.z, bb.w};
#pragma unroll
  for (int i2 = 0; i2 < 4; ++i2) {
    float4 o;
    o.x = fmaxf(acc[i2][0] + ba[0], 0.f);
    o.y = fmaxf(acc[i2][1] + ba[1], 0.f);
    o.z = fmaxf(acc[i2][2] + ba[2], 0.f);
    o.w = fmaxf(acc[i2][3] + ba[3], 0.f);
    ((float4*)h)[(nb + 4*a + i2) * 32 + bq] = o;
  }
}

// ---------------------------------------------------------------------------
// CSR build: histogram -> scan -> fill
// ---------------------------------------------------------------------------
__global__ __launch_bounds__(256) void k_hist(const int* __restrict__ dst,
                                              int* __restrict__ deg) {
  int e = blockIdx.x * 256 + threadIdx.x;
  if (e < N_EDGES) atomicAdd(&deg[dst[e]], 1);
}

#define SCAN_CHUNK 4096
#define SCAN_NB 25

__global__ __launch_bounds__(256) void k_scan_part(const int* __restrict__ deg,
                                                   int* __restrict__ bsum) {
  __shared__ int red[256];
  int t = threadIdx.x, b = blockIdx.x;
  int base = b * SCAN_CHUNK + t * 16;
  int s = 0;
#pragma unroll
  for (int i = 0; i < 16; ++i) {
    int idx = base + i;
    if (idx < N_NODES) s += deg[idx];
  }
  red[t] = s;
  __syncthreads();
  for (int off = 128; off > 0; off >>= 1) {
    if (t < off) red[t] += red[t + off];
    __syncthreads();
  }
  if (t == 0) bsum[b] = red[0];
}

__global__ void k_scan_mid(const int* __restrict__ bsum, int* __restrict__ boff,
                           int* __restrict__ rowstart) {
  if (threadIdx.x == 0) {
    int run = 0;
    for (int i = 0; i < SCAN_NB; ++i) { boff[i] = run; run += bsum[i]; }
    rowstart[N_NODES] = run;
  }
}

__global__ __launch_bounds__(256) void k_scan_final(const int* __restrict__ deg,
                                                    const int* __restrict__ boff,
                                                    int* __restrict__ rowstart) {
  __shared__ int ts[256];
  int t = threadIdx.x, b = blockIdx.x;
  int base = b * SCAN_CHUNK + t * 16;
  int v[16];
  int s = 0;
#pragma unroll
  for (int i = 0; i < 16; ++i) {
    int idx = base + i;
    v[i] = (idx < N_NODES) ? deg[idx] : 0;
    s += v[i];
  }
  ts[t] = s;
  __syncthreads();
  for (int off = 1; off < 256; off <<= 1) {
    int add = (t >= off) ? ts[t - off] : 0;
    __syncthreads();
    ts[t] += add;
    __syncthreads();
  }
  int run = boff[b] + ts[t] - s;
#pragma unroll
  for (int i = 0; i < 16; ++i) {
    int idx = base + i;
    if (idx < N_NODES) rowstart[idx] = run;
    run += v[i];
  }
}

__global__ __launch_bounds__(256) void k_fill(const int* __restrict__ src,
                                              const int* __restrict__ dst,
                                              int* __restrict__ cursor,
                                              int* __restrict__ srcSorted) {
  int e = blockIdx.x * 256 + threadIdx.x;
  if (e >= N_EDGES) return;
  int d = dst[e];
  int p = atomicAdd(&cursor[d], 1);
  srcSorted[p] = src[e];
}

// ---------------------------------------------------------------------------
// One-time weight split fp32 -> bf16 (hi, lo). Layout preserved: [mat][j][k]
// ---------------------------------------------------------------------------
__global__ __launch_bounds__(256) void k_wsplit(const float* __restrict__ W0,
                                                const float* __restrict__ W1,
                                                const float* __restrict__ W2,
                                                const float* __restrict__ W3,
                                                __bf16* __restrict__ Whi,
                                                __bf16* __restrict__ Wlo) {
  int id = blockIdx.x * 256 + threadIdx.x;  // 65536 total
  int mat = id >> 14, idx = id & 16383;
  const float* W = (mat == 0) ? W0 : (mat == 1) ? W1 : (mat == 2) ? W2 : W3;
  float v = W[idx];
  __bf16 hi = (__bf16)v;
  Whi[id] = hi;
  Wlo[id] = (__bf16)(v - (float)hi);
}

// ---------------------------------------------------------------------------
// Aggregation (gather): m[n] = sum_{j in CSR[n]} h[srcSorted[j]]
// ---------------------------------------------------------------------------
__global__ __launch_bounds__(256) void k_gather(const float* __restrict__ h,
                                                const int* __restrict__ rowstart,
                                                const int* __restrict__ srcSorted,
                                                float* __restrict__ m) {
  int node = blockIdx.x * 4 + (threadIdx.x >> 6);
  if (node >= N_NODES) return;
  int l = threadIdx.x & 63;
  int j0 = rowstart[node], j1 = rowstart[node + 1];
  const float2* h2 = (const float2*)h;
  float2 a0 = {0.f, 0.f}, a1 = {0.f, 0.f};
  int j = j0;
  for (; j + 1 < j1; j += 2) {
    int s0 = srcSorted[j], s1 = srcSorted[j + 1];
    float2 v0 = h2[s0 * 64 + l];
    float2 v1 = h2[s1 * 64 + l];
    a0.x += v0.x; a0.y += v0.y;
    a1.x += v1.x; a1.y += v1.y;
  }
  if (j < j1) {
    int s0 = srcSorted[j];
    float2 v0 = h2[s0 * 64 + l];
    a0.x += v0.x; a0.y += v0.y;
  }
  float2 o = {a0.x + a1.x, a0.y + a1.y};
  ((float2*)m)[node * 64 + l] = o;
}

// ---------------------------------------------------------------------------
// Fused MGU update, MFMA split-bf16, in-place on h.
// v4: fast transcendentals, kc loops unrolled, VGPR capped at 4 waves/SIMD
// (LDS 34,816 B -> 4 blocks/CU = 16 waves/CU).
// ---------------------------------------------------------------------------
__global__ __launch_bounds__(256, 4) void k_mgu(float* __restrict__ h,
                                             const float* __restrict__ m,
                                             const __bf16* __restrict__ Whi,
                                             const __bf16* __restrict__ Wlo,
                                             const float* __restrict__ bfp,
                                             const float* __restrict__ bhp) {
  __shared__ __bf16 mHi[32 * LDST], mLo[32 * LDST];
  __shared__ __bf16 hHi[32 * LDST], hLo[32 * LDST];  // becomes g after f-gate
  const int t = threadIdx.x;
  const int nb = blockIdx.x * 32;

#pragma unroll
  for (int i = 0; i < 4; ++i) {
    int idx4 = i * 256 + t;
    int n = idx4 >> 5, kq = idx4 & 31;
    float4 vm = ((const float4*)m)[(nb + n) * 32 + kq];
    float4 vh = ((const float4*)h)[(nb + n) * 32 + kq];
    bf16x4 mh, ml, hh, hl;
    mh[0] = (__bf16)vm.x; ml[0] = (__bf16)(vm.x - (float)mh[0]);
    mh[1] = (__bf16)vm.y; ml[1] = (__bf16)(vm.y - (float)mh[1]);
    mh[2] = (__bf16)vm.z; ml[2] = (__bf16)(vm.z - (float)mh[2]);
    mh[3] = (__bf16)vm.w; ml[3] = (__bf16)(vm.w - (float)mh[3]);
    hh[0] = (__bf16)vh.x; hl[0] = (__bf16)(vh.x - (float)hh[0]);
    hh[1] = (__bf16)vh.y; hl[1] = (__bf16)(vh.y - (float)hh[1]);
    hh[2] = (__bf16)vh.z; hl[2] = (__bf16)(vh.z - (float)hh[2]);
    hh[3] = (__bf16)vh.w; hl[3] = (__bf16)(vh.w - (float)hh[3]);
    int e0 = n * LDST + 4 * kq;
    *(bf16x4*)&mHi[e0] = mh; *(bf16x4*)&mLo[e0] = ml;
    *(bf16x4*)&hHi[e0] = hh; *(bf16x4*)&hLo[e0] = hl;
  }
  __syncthreads();

  const int w = t >> 6, l = t & 63;
  const int lj = l & 15, q = l >> 4;

  float bfj[2], bhj[2];
#pragma unroll
  for (int ct = 0; ct < 2; ++ct) {
    int j = (2 * w + ct) * 16 + lj;
    bfj[ct] = bfp[j];
    bhj[ct] = bhp[j];
  }

  f32x4 acc[2][2] = {};

  // ---- phase A: z_f = m@Wf.T + h@Uf.T ----
#pragma unroll
  for (int kc = 0; kc < 128; kc += 32) {
    bf16x8 amh[2], aml[2], ahh[2], ahl[2];
#pragma unroll
    for (int rt = 0; rt < 2; ++rt) {
      int e0 = (rt * 16 + lj) * LDST + kc + q * 8;
      amh[rt] = *(const bf16x8*)&mHi[e0];
      aml[rt] = *(const bf16x8*)&mLo[e0];
      ahh[rt] = *(const bf16x8*)&hHi[e0];
      ahl[rt] = *(const bf16x8*)&hLo[e0];
    }
    bf16x8 bwh[2], bwl[2], buh[2], bul[2];
#pragma unroll
    for (int ct = 0; ct < 2; ++ct) {
      int off = ((2 * w + ct) * 16 + lj) * 128 + kc + q * 8;
      bwh[ct] = *(const bf16x8*)&Whi[off];
      bwl[ct] = *(const bf16x8*)&Wlo[off];
      buh[ct] = *(const bf16x8*)&Whi[16384 + off];
      bul[ct] = *(const bf16x8*)&Wlo[16384 + off];
    }
#pragma unroll
    for (int rt = 0; rt < 2; ++rt)
#pragma unroll
      for (int ct = 0; ct < 2; ++ct) {
        f32x4 a = acc[rt][ct];
        a = __builtin_amdgcn_mfma_f32_16x16x32_bf16(amh[rt], bwh[ct], a, 0, 0, 0);
        a = __builtin_amdgcn_mfma_f32_16x16x32_bf16(amh[rt], bwl[ct], a, 0, 0, 0);
        a = __builtin_amdgcn_mfma_f32_16x16x32_bf16(aml[rt], bwh[ct], a, 0, 0, 0);
        a = __builtin_amdgcn_mfma_f32_16x16x32_bf16(ahh[rt], buh[ct], a, 0, 0, 0);
        a = __builtin_amdgcn_mfma_f32_16x16x32_bf16(ahh[rt], bul[ct], a, 0, 0, 0);
        a = __builtin_amdgcn_mfma_f32_16x16x32_bf16(ahl[rt], buh[ct], a, 0, 0, 0);
        acc[rt][ct] = a;
      }
  }

  // ---- transition: f = sigmoid(z_f + bf); g = f*h overwrites h tile ----
  __syncthreads();  // all phase-A reads of hHi/hLo complete
  float fv[2][2][4], hvv[2][2][4];
#pragma unroll
  for (int rt = 0; rt < 2; ++rt)
#pragma unroll
    for (int ct = 0; ct < 2; ++ct) {
      int j = (2 * w + ct) * 16 + lj;
#pragma unroll
      for (int r = 0; r < 4; ++r) {
        int nl = rt * 16 + q * 4 + r;
        float z = acc[rt][ct][r] + bfj[ct];
        float f = sigmoid_f(z);
        int he = nl * LDST + j;
        float hval = (float)hHi[he] + (float)hLo[he];
        float g = f * hval;
        __bf16 ghi = (__bf16)g;
        hHi[he] = ghi;
        hLo[he] = (__bf16)(g - (float)ghi);
        fv[rt][ct][r] = f;
        hvv[rt][ct][r] = hval;
        acc[rt][ct][r] = 0.f;
      }
    }
  __syncthreads();

  // ---- phase B: z_h = m@Wh.T + g@Uh.T ----
#pragma unroll
  for (int kc = 0; kc < 128; kc += 32) {
    bf16x8 amh[2], aml[2], agh[2], agl[2];
#pragma unroll
    for (int rt = 0; rt < 2; ++rt) {
      int e0 = (rt * 16 + lj) * LDST + kc + q * 8;
      amh[rt] = *(const bf16x8*)&mHi[e0];
      aml[rt] = *(const bf16x8*)&mLo[e0];
      agh[rt] = *(const bf16x8*)&hHi[e0];
      agl[rt] = *(const bf16x8*)&hLo[e0];
    }
    bf16x8 bwh[2], bwl[2], buh[2], bul[2];
#pragma unroll
    for (int ct = 0; ct < 2; ++ct) {
      int off = ((2 * w + ct) * 16 + lj) * 128 + kc + q * 8;
      bwh[ct] = *(const bf16x8*)&Whi[2 * 16384 + off];
      bwl[ct] = *(const bf16x8*)&Wlo[2 * 16384 + off];
      buh[ct] = *(const bf16x8*)&Whi[3 * 16384 + off];
      bul[ct] = *(const bf16x8*)&Wlo[3 * 16384 + off];
    }
#pragma unroll
    for (int rt = 0; rt < 2; ++rt)
#pragma unroll
      for (int ct = 0; ct < 2; ++ct) {
        f32x4 a = acc[rt][ct];
        a = __builtin_amdgcn_mfma_f32_16x16x32_bf16(amh[rt], bwh[ct], a, 0, 0, 0);
        a = __builtin_amdgcn_mfma_f32_16x16x32_bf16(amh[rt], bwl[ct], a, 0, 0, 0);
        a = __builtin_amdgcn_mfma_f32_16x16x32_bf16(aml[rt], bwh[ct], a, 0, 0, 0);
        a = __builtin_amdgcn_mfma_f32_16x16x32_bf16(agh[rt], buh[ct], a, 0, 0, 0);
        a = __builtin_amdgcn_mfma_f32_16x16x32_bf16(agh[rt], bul[ct], a, 0, 0, 0);
        a = __builtin_amdgcn_mfma_f32_16x16x32_bf16(agl[rt], buh[ct], a, 0, 0, 0);
        acc[rt][ct] = a;
      }
  }

  // ---- epilogue: h = (1-f)*h + f*tanh(z_h + bh) ----
#pragma unroll
  for (int rt = 0; rt < 2; ++rt)
#pragma unroll
    for (int ct = 0; ct < 2; ++ct) {
      int j = (2 * w + ct) * 16 + lj;
#pragma unroll
      for (int r = 0; r < 4; ++r) {
        float T = tanh_f(acc[rt][ct][r] + bhj[ct]);
        float f = fv[rt][ct][r];
        float hn = (1.f - f) * hvv[rt][ct][r] + f * T;
        h[(nb + rt * 16 + q * 4 + r) * 128 + j] = hn;
      }
    }
}

// ---------------------------------------------------------------------------
// Whole Set2Set in ONE kernel, flash-style fused attention, unroll-2 streams.
// ---------------------------------------------------------------------------
__global__ __launch_bounds__(1024) void k_s2s(const float* __restrict__ h,
                                              const int* __restrict__ batch,
                                              const float* __restrict__ w_ih,
                                              const float* __restrict__ w_hh,
                                              const float* __restrict__ b_ih,
                                              const float* __restrict__ b_hh,
                                              const float* __restrict__ Wp,
                                              const float* __restrict__ bp,
                                              float* __restrict__ out) {
  const int g = blockIdx.x, t = threadIdx.x;
  const int w = t >> 6, l = t & 63;
  const int half = l >> 5, li = l & 31;
  const int hw = 2 * w + half;           // stream id 0..31
  __shared__ float qs[256];              // q_star = [q | r]
  __shared__ float hl[128], cl[128];
  __shared__ float gates[512];
  __shared__ float redM[32], redS[32], scl[32];
  __shared__ float rPart[32][132];       // row stride 528 B (16B aligned)
  __shared__ float gInvS;
  __shared__ int bnd[2];

  if (t < 2) {
    int tgt = g + t;
    int lo = 0, hi = N_NODES;
    while (lo < hi) { int mid = (lo + hi) >> 1; if (batch[mid] < tgt) lo = mid + 1; else hi = mid; }
    bnd[t] = lo;
  }
  if (t < 256) qs[t] = 0.f;
  if (t < 128) { hl[t] = 0.f; cl[t] = 0.f; }
  __syncthreads();
  const int s0 = bnd[0], s1 = bnd[1];

  for (int step = 0; step < 3; ++step) {
    // ---- LSTM gates: [512] = q_star@w_ih.T + h_l@w_hh.T + biases ----
#pragma unroll 2
    for (int jt = w; jt < 512; jt += 16) {
      const float* wi = w_ih + jt * 256;
      const float* wh = w_hh + jt * 128;
      float s = qs[l] * wi[l] + qs[l+64] * wi[l+64]
              + qs[l+128] * wi[l+128] + qs[l+192] * wi[l+192]
              + hl[l] * wh[l] + hl[l+64] * wh[l+64];
#pragma unroll
      for (int o = 32; o > 0; o >>= 1) s += __shfl_xor(s, o, 64);
      if (l == 0) gates[jt] = s + b_ih[jt] + b_hh[jt];
    }
    __syncthreads();
    if (t < 128) {
      float gi = gates[t], gf = gates[128 + t], gg = gates[256 + t], go = gates[384 + t];
      float c = sigmoid_f(gf) * cl[t] + sigmoid_f(gi) * tanh_f(gg);
      float hh = sigmoid_f(go) * tanh_f(c);
      cl[t] = c;
      hl[t] = hh;
      qs[t] = hh;  // q part
    }
    __syncthreads();

    // ---- fused attention (online softmax, single pass, 2 nodes in flight) ----
    float mw = -INFINITY, sw = 0.f;
    float4 racc = {0.f, 0.f, 0.f, 0.f};
    const float4* h4 = (const float4*)h;
    const float q0 = qs[4*li], q1 = qs[4*li+1], q2 = qs[4*li+2], q3 = qs[4*li+3];
    int n = s0 + hw;
    for (; n + 32 < s1; n += 64) {
      float4 hv0 = h4[n * 32 + li];
      float4 hv1 = h4[(n + 32) * 32 + li];
      float v0 = hv0.x * q0 + hv0.y * q1 + hv0.z * q2 + hv0.w * q3;
      float v1 = hv1.x * q0 + hv1.y * q1 + hv1.z * q2 + hv1.w * q3;
#pragma unroll
      for (int o = 16; o > 0; o >>= 1) {
        v0 += __shfl_xor(v0, o, 64);
        v1 += __shfl_xor(v1, o, 64);
      }
      float nm = fmaxf(mw, fmaxf(v0, v1));
      float sc = __expf(mw - nm);
      float w0 = __expf(v0 - nm);
      float w1 = __expf(v1 - nm);
      sw = sw * sc + w0 + w1;
      racc.x = racc.x * sc + w0 * hv0.x + w1 * hv1.x;
      racc.y = racc.y * sc + w0 * hv0.y + w1 * hv1.y;
      racc.z = racc.z * sc + w0 * hv0.z + w1 * hv1.z;
      racc.w = racc.w * sc + w0 * hv0.w + w1 * hv1.w;
      mw = nm;
    }
    for (; n < s1; n += 32) {
      float4 hv = h4[n * 32 + li];
      float v = hv.x * q0 + hv.y * q1 + hv.z * q2 + hv.w * q3;
#pragma unroll
      for (int o = 16; o > 0; o >>= 1) v += __shfl_xor(v, o, 64);
      float nm = fmaxf(mw, v);
      float sc = __expf(mw - nm);
      float wg = __expf(v - nm);
      sw = sw * sc + wg;
      racc.x = racc.x * sc + wg * hv.x;
      racc.y = racc.y * sc + wg * hv.y;
      racc.z = racc.z * sc + wg * hv.z;
      racc.w = racc.w * sc + wg * hv.w;
      mw = nm;
    }
    if (li == 0) { redM[hw] = mw; redS[hw] = sw; }
    *(float4*)&rPart[hw][4 * li] = racc;
    __syncthreads();
    if (t == 0) {
      float M = -INFINITY;
      for (int i = 0; i < 32; ++i) M = fmaxf(M, redM[i]);
      float S = 0.f;
      for (int i = 0; i < 32; ++i) {
        float s_ = (redM[i] > -INFINITY && M > -INFINITY) ? __expf(redM[i] - M) : 0.f;
        scl[i] = s_;
        S += redS[i] * s_;
      }
      gInvS = (S > 0.f) ? __fdividef(1.f, S) : 0.f;
    }
    __syncthreads();
    if (t < 128) {
      float inv = gInvS;
      float r = 0.f;
#pragma unroll
      for (int i = 0; i < 32; ++i) r += rPart[i][t] * scl[i];
      qs[128 + t] = r * inv;
    }
    __syncthreads();
  }

  // ---- prediction: out[g] = <q_star, W_pred> + b ----
  __shared__ float pr[256];
  if (t < 256) pr[t] = qs[t] * Wp[t];
  __syncthreads();
  if (t < 128) pr[t] += pr[t + 128];
  __syncthreads();
  if (t < 64) {
    float s = pr[t] + pr[t + 64];
#pragma unroll
    for (int o = 32; o > 0; o >>= 1) s += __shfl_xor(s, o, 64);
    if (t == 0) out[g] = s + bp[0];
  }
}

// ---------------------------------------------------------------------------
extern "C" void kernel_launch(void* const* d_in, const int* in_sizes, int n_in,
                              void* d_out, int out_size, void* d_ws, size_t ws_size,
                              hipStream_t stream) {
  const float* x      = (const float*)d_in[0];
  const int*   ei     = (const int*)d_in[1];
  const int*   batch  = (const int*)d_in[2];
  const float* W_in   = (const float*)d_in[3];
  const float* b_in   = (const float*)d_in[4];
  const float* W_f    = (const float*)d_in[5];
  const float* U_f    = (const float*)d_in[6];
  const float* b_f    = (const float*)d_in[7];
  const float* W_h    = (const float*)d_in[8];
  const float* U_h    = (const float*)d_in[9];
  const float* b_h    = (const float*)d_in[10];
  const float* w_ih   = (const float*)d_in[11];
  const float* w_hh   = (const float*)d_in[12];
  const float* b_ih   = (const float*)d_in[13];
  const float* b_hh   = (const float*)d_in[14];
  const float* W_pred = (const float*)d_in[15];
  const float* b_pred = (const float*)d_in[16];
  float* out = (float*)d_out;

  char* ws = (char*)d_ws;
  float* h      = (float*)(ws);                    // 51,200,000 B
  float* m      = (float*)(ws + 51200000);         // 51,200,000 B
  int*   rowstart = (int*)(ws + 103063808);        //    400,016 B
  int*   srcSorted= (int*)(ws + 103463824);        //  2,560,000 B
  int*   bsum   = (int*)  (ws + 106023824);        //        112 B
  int*   boff   = (int*)  (ws + 106023936);        //        112 B
  // region at +102,400,000 (400,000 B): deg/cursor (CSR build) then Whi/Wlo
  int*    deg    = (int*)(ws + 102400000);
  int*    cursor = (int*)(ws + 102400000);
  __bf16* Whi    = (__bf16*)(ws + 102400000);      //    131,072 B
  __bf16* Wlo    = (__bf16*)(ws + 102531072);      //    131,072 B

  const int* src = ei;
  const int* dst = ei + N_EDGES;

  // ---- CSR build (once; reused by all 3 MPNN steps) ----
  hipMemsetAsync(deg, 0, N_NODES * 4, stream);
  k_hist<<<(N_EDGES + 255) / 256, 256, 0, stream>>>(dst, deg);
  k_scan_part<<<SCAN_NB, 256, 0, stream>>>(deg, bsum);
  k_scan_mid<<<1, 32, 0, stream>>>(bsum, boff, rowstart);
  k_scan_final<<<SCAN_NB, 256, 0, stream>>>(deg, boff, rowstart);
  hipMemcpyAsync(cursor, rowstart, N_NODES * 4, hipMemcpyDeviceToDevice, stream);
  k_fill<<<(N_EDGES + 255) / 256, 256, 0, stream>>>(src, dst, cursor, srcSorted);

  // ---- one-time weight bf16 hi/lo split (overwrites deg/cursor region) ----
  k_wsplit<<<256, 256, 0, stream>>>(W_f, U_f, W_h, U_h, Whi, Wlo);

  k_input<<<N_NODES / 32, 256, 0, stream>>>(x, W_in, b_in, h);

  for (int step = 0; step < 3; ++step) {
    k_gather<<<(N_NODES + 3) / 4, 256, 0, stream>>>(h, rowstart, srcSorted, m);
    k_mgu<<<N_NODES / 32, 256, 0, stream>>>(h, m, Whi, Wlo, b_f, b_h);
  }

  // ---- entire Set2Set + prediction in one launch ----
  k_s2s<<<NGRAPH, 1024, 0, stream>>>(h, batch, w_ih, w_hh, b_ih, b_hh,
                                     W_pred, b_pred, out);
}

// Round 9
// 721.759 us; speedup vs baseline: 2.4244x; 1.0995x over previous
//
#include <hip/hip_runtime.h>
#include <math.h>

#define N_NODES 100000
#define N_EDGES 640000
#define IN_DIM 64
#define HID 128
#define NGRAPH 128

typedef __bf16 bf16x2 __attribute__((ext_vector_type(2)));
typedef __bf16 bf16x4 __attribute__((ext_vector_type(4)));
typedef __bf16 bf16x8 __attribute__((ext_vector_type(8)));
typedef float f32x4 __attribute__((ext_vector_type(4)));

#define LDST 136  // bf16 elements per LDS row: 272 B, 16B-aligned, breaks pow2 stride

// fast transcendentals; inf-safe at both ends.
__device__ __forceinline__ float sigmoid_f(float z) {
  return __fdividef(1.f, 1.f + __expf(-z));
}
__device__ __forceinline__ float tanh_f(float z) {
  return 1.f - __fdividef(2.f, __expf(2.f * z) + 1.f);
}

// ---------------------------------------------------------------------------
// fma helper (used by k_input only)
// ---------------------------------------------------------------------------
__device__ __forceinline__ void fma44(const float4 A[4], const float4 B[4], float acc[4][4]) {
#pragma unroll
  for (int i2 = 0; i2 < 4; ++i2) {
    acc[i2][0] += A[i2].x*B[0].x + A[i2].y*B[1].x + A[i2].z*B[2].x + A[i2].w*B[3].x;
    acc[i2][1] += A[i2].x*B[0].y + A[i2].y*B[1].y + A[i2].z*B[2].y + A[i2].w*B[3].y;
    acc[i2][2] += A[i2].x*B[0].z + A[i2].y*B[1].z + A[i2].z*B[2].z + A[i2].w*B[3].z;
    acc[i2][3] += A[i2].x*B[0].w + A[i2].y*B[1].w + A[i2].z*B[2].w + A[i2].w*B[3].w;
  }
}

// ---------------------------------------------------------------------------
// Kernel 1: h = relu(x @ W_in.T + b_in)
// ---------------------------------------------------------------------------
__global__ __launch_bounds__(256) void k_input(const float* __restrict__ x,
                                               const float* __restrict__ W,
                                               const float* __restrict__ b,
                                               float* __restrict__ h) {
  __shared__ float wS[64][132];
  __shared__ float xS[32][68];
  int t = threadIdx.x;
  int nb = blockIdx.x * 32;
#pragma unroll
  for (int i = 0; i < 8; ++i) {
    int idx4 = i * 256 + t;
    int j = idx4 >> 4, kq = idx4 & 15;
    float4 v = ((const float4*)W)[j * 16 + kq];
    wS[4*kq+0][j] = v.x; wS[4*kq+1][j] = v.y; wS[4*kq+2][j] = v.z; wS[4*kq+3][j] = v.w;
  }
#pragma unroll
  for (int i = 0; i < 2; ++i) {
    int idx4 = i * 256 + t;
    int n = idx4 >> 4, kq = idx4 & 15;
    float4 v = ((const float4*)x)[(nb + n) * 16 + kq];
    *((float4*)&xS[n][4*kq]) = v;
  }
  __syncthreads();
  int bq = t & 31, a = t >> 5;
  float acc[4][4] = {};
#pragma unroll
  for (int kk4 = 0; kk4 < 16; ++kk4) {
    float4 A[4], B[4];
#pragma unroll
    for (int i2 = 0; i2 < 4; ++i2) A[i2] = *((const float4*)&xS[4*a+i2][4*kk4]);
#pragma unroll
    for (int c = 0; c < 4; ++c) B[c] = *((const float4*)&wS[4*kk4+c][4*bq]);
    fma44(A, B, acc);
  }
  float4 bb = ((const float4*)b)[bq];
  float ba[4] = {bb.x, bb.y, bb.z, bb.w};
#pragma unroll
  for (int i2 = 0; i2 < 4; ++i2) {
    float4 o;
    o.x = fmaxf(acc[i2][0] + ba[0], 0.f);
    o.y = fmaxf(acc[i2][1] + ba[1], 0.f);
    o.z = fmaxf(acc[i2][2] + ba[2], 0.f);
    o.w = fmaxf(acc[i2][3] + ba[3], 0.f);
    ((float4*)h)[(nb + 4*a + i2) * 32 + bq] = o;
  }
}

// ---------------------------------------------------------------------------
// CSR build: histogram -> scan -> fill
// ---------------------------------------------------------------------------
__global__ __launch_bounds__(256) void k_hist(const int* __restrict__ dst,
                                              int* __restrict__ deg) {
  int e = blockIdx.x * 256 + threadIdx.x;
  if (e < N_EDGES) atomicAdd(&deg[dst[e]], 1);
}

#define SCAN_CHUNK 4096
#define SCAN_NB 25

__global__ __launch_bounds__(256) void k_scan_part(const int* __restrict__ deg,
                                                   int* __restrict__ bsum) {
  __shared__ int red[256];
  int t = threadIdx.x, b = blockIdx.x;
  int base = b * SCAN_CHUNK + t * 16;
  int s = 0;
#pragma unroll
  for (int i = 0; i < 16; ++i) {
    int idx = base + i;
    if (idx < N_NODES) s += deg[idx];
  }
  red[t] = s;
  __syncthreads();
  for (int off = 128; off > 0; off >>= 1) {
    if (t < off) red[t] += red[t + off];
    __syncthreads();
  }
  if (t == 0) bsum[b] = red[0];
}

__global__ void k_scan_mid(const int* __restrict__ bsum, int* __restrict__ boff,
                           int* __restrict__ rowstart) {
  if (threadIdx.x == 0) {
    int run = 0;
    for (int i = 0; i < SCAN_NB; ++i) { boff[i] = run; run += bsum[i]; }
    rowstart[N_NODES] = run;
  }
}

__global__ __launch_bounds__(256) void k_scan_final(const int* __restrict__ deg,
                                                    const int* __restrict__ boff,
                                                    int* __restrict__ rowstart) {
  __shared__ int ts[256];
  int t = threadIdx.x, b = blockIdx.x;
  int base = b * SCAN_CHUNK + t * 16;
  int v[16];
  int s = 0;
#pragma unroll
  for (int i = 0; i < 16; ++i) {
    int idx = base + i;
    v[i] = (idx < N_NODES) ? deg[idx] : 0;
    s += v[i];
  }
  ts[t] = s;
  __syncthreads();
  for (int off = 1; off < 256; off <<= 1) {
    int add = (t >= off) ? ts[t - off] : 0;
    __syncthreads();
    ts[t] += add;
    __syncthreads();
  }
  int run = boff[b] + ts[t] - s;
#pragma unroll
  for (int i = 0; i < 16; ++i) {
    int idx = base + i;
    if (idx < N_NODES) rowstart[idx] = run;
    run += v[i];
  }
}

__global__ __launch_bounds__(256) void k_fill(const int* __restrict__ src,
                                              const int* __restrict__ dst,
                                              int* __restrict__ cursor,
                                              int* __restrict__ srcSorted) {
  int e = blockIdx.x * 256 + threadIdx.x;
  if (e >= N_EDGES) return;
  int d = dst[e];
  int p = atomicAdd(&cursor[d], 1);
  srcSorted[p] = src[e];
}

// ---------------------------------------------------------------------------
// One-time weight split fp32 -> bf16 (hi, lo). Layout preserved: [mat][j][k]
// ---------------------------------------------------------------------------
__global__ __launch_bounds__(256) void k_wsplit(const float* __restrict__ W0,
                                                const float* __restrict__ W1,
                                                const float* __restrict__ W2,
                                                const float* __restrict__ W3,
                                                __bf16* __restrict__ Whi,
                                                __bf16* __restrict__ Wlo) {
  int id = blockIdx.x * 256 + threadIdx.x;  // 65536 total
  int mat = id >> 14, idx = id & 16383;
  const float* W = (mat == 0) ? W0 : (mat == 1) ? W1 : (mat == 2) ? W2 : W3;
  float v = W[idx];
  __bf16 hi = (__bf16)v;
  Whi[id] = hi;
  Wlo[id] = (__bf16)(v - (float)hi);
}

// ---------------------------------------------------------------------------
// Aggregation (gather): m[n] = sum_{j in CSR[n]} h[srcSorted[j]]
// 32 lanes x float4 per node (one b128/lane/edge), 8 nodes/block, 2 in flight.
// ---------------------------------------------------------------------------
__global__ __launch_bounds__(256) void k_gather(const float* __restrict__ h,
                                                const int* __restrict__ rowstart,
                                                const int* __restrict__ srcSorted,
                                                float* __restrict__ m) {
  int node = blockIdx.x * 8 + (threadIdx.x >> 5);
  if (node >= N_NODES) return;
  int li = threadIdx.x & 31;
  int j0 = rowstart[node], j1 = rowstart[node + 1];
  const float4* h4 = (const float4*)h;
  float4 a0 = {0.f, 0.f, 0.f, 0.f}, a1 = {0.f, 0.f, 0.f, 0.f};
  int j = j0;
  for (; j + 1 < j1; j += 2) {
    int s0 = srcSorted[j], s1 = srcSorted[j + 1];
    float4 v0 = h4[s0 * 32 + li];
    float4 v1 = h4[s1 * 32 + li];
    a0.x += v0.x; a0.y += v0.y; a0.z += v0.z; a0.w += v0.w;
    a1.x += v1.x; a1.y += v1.y; a1.z += v1.z; a1.w += v1.w;
  }
  if (j < j1) {
    int s0 = srcSorted[j];
    float4 v0 = h4[s0 * 32 + li];
    a0.x += v0.x; a0.y += v0.y; a0.z += v0.z; a0.w += v0.w;
  }
  float4 o = {a0.x + a1.x, a0.y + a1.y, a0.z + a1.z, a0.w + a1.w};
  ((float4*)m)[node * 32 + li] = o;
}

// ---------------------------------------------------------------------------
// Fused MGU update, MFMA split-bf16, in-place on h.
// v5: 64 nodes/block, 256 threads, acc[4][2]/wave (8 independent MFMA chains).
// Weight fetch per node halved; LDS 69,632 B -> 2 blocks/CU.
// ---------------------------------------------------------------------------
__global__ __launch_bounds__(256) void k_mgu(float* __restrict__ h,
                                             const float* __restrict__ m,
                                             const __bf16* __restrict__ Whi,
                                             const __bf16* __restrict__ Wlo,
                                             const float* __restrict__ bfp,
                                             const float* __restrict__ bhp) {
  __shared__ __bf16 mHi[64 * LDST], mLo[64 * LDST];
  __shared__ __bf16 hHi[64 * LDST], hLo[64 * LDST];  // becomes g after f-gate
  const int t = threadIdx.x;
  const int nb = blockIdx.x * 64;

  // stage 64 rows x 128 of m and h, split to bf16 hi/lo
#pragma unroll
  for (int i = 0; i < 8; ++i) {
    int idx4 = i * 256 + t;
    int n = idx4 >> 5, kq = idx4 & 31;
    float4 vm = ((const float4*)m)[(nb + n) * 32 + kq];
    float4 vh = ((const float4*)h)[(nb + n) * 32 + kq];
    bf16x4 mh, ml, hh, hl;
    mh[0] = (__bf16)vm.x; ml[0] = (__bf16)(vm.x - (float)mh[0]);
    mh[1] = (__bf16)vm.y; ml[1] = (__bf16)(vm.y - (float)mh[1]);
    mh[2] = (__bf16)vm.z; ml[2] = (__bf16)(vm.z - (float)mh[2]);
    mh[3] = (__bf16)vm.w; ml[3] = (__bf16)(vm.w - (float)mh[3]);
    hh[0] = (__bf16)vh.x; hl[0] = (__bf16)(vh.x - (float)hh[0]);
    hh[1] = (__bf16)vh.y; hl[1] = (__bf16)(vh.y - (float)hh[1]);
    hh[2] = (__bf16)vh.z; hl[2] = (__bf16)(vh.z - (float)hh[2]);
    hh[3] = (__bf16)vh.w; hl[3] = (__bf16)(vh.w - (float)hh[3]);
    int e0 = n * LDST + 4 * kq;
    *(bf16x4*)&mHi[e0] = mh; *(bf16x4*)&mLo[e0] = ml;
    *(bf16x4*)&hHi[e0] = hh; *(bf16x4*)&hLo[e0] = hl;
  }
  __syncthreads();

  const int w = t >> 6, l = t & 63;
  const int lj = l & 15, q = l >> 4;

  float bfj[2], bhj[2];
#pragma unroll
  for (int ct = 0; ct < 2; ++ct) {
    int j = (2 * w + ct) * 16 + lj;
    bfj[ct] = bfp[j];
    bhj[ct] = bhp[j];
  }

  f32x4 acc[4][2] = {};

  // ---- phase A: z_f = m@Wf.T + h@Uf.T ----
#pragma unroll
  for (int kc = 0; kc < 128; kc += 32) {
    bf16x8 bwh[2], bwl[2], buh[2], bul[2];
#pragma unroll
    for (int ct = 0; ct < 2; ++ct) {
      int off = ((2 * w + ct) * 16 + lj) * 128 + kc + q * 8;
      bwh[ct] = *(const bf16x8*)&Whi[off];
      bwl[ct] = *(const bf16x8*)&Wlo[off];
      buh[ct] = *(const bf16x8*)&Whi[16384 + off];
      bul[ct] = *(const bf16x8*)&Wlo[16384 + off];
    }
#pragma unroll
    for (int rt = 0; rt < 4; ++rt) {
      int e0 = (rt * 16 + lj) * LDST + kc + q * 8;
      bf16x8 amh = *(const bf16x8*)&mHi[e0];
      bf16x8 aml = *(const bf16x8*)&mLo[e0];
      bf16x8 ahh = *(const bf16x8*)&hHi[e0];
      bf16x8 ahl = *(const bf16x8*)&hLo[e0];
#pragma unroll
      for (int ct = 0; ct < 2; ++ct) {
        f32x4 a = acc[rt][ct];
        a = __builtin_amdgcn_mfma_f32_16x16x32_bf16(amh, bwh[ct], a, 0, 0, 0);
        a = __builtin_amdgcn_mfma_f32_16x16x32_bf16(amh, bwl[ct], a, 0, 0, 0);
        a = __builtin_amdgcn_mfma_f32_16x16x32_bf16(aml, bwh[ct], a, 0, 0, 0);
        a = __builtin_amdgcn_mfma_f32_16x16x32_bf16(ahh, buh[ct], a, 0, 0, 0);
        a = __builtin_amdgcn_mfma_f32_16x16x32_bf16(ahh, bul[ct], a, 0, 0, 0);
        a = __builtin_amdgcn_mfma_f32_16x16x32_bf16(ahl, buh[ct], a, 0, 0, 0);
        acc[rt][ct] = a;
      }
    }
  }

  // ---- transition: f = sigmoid(z_f + bf); g = f*h overwrites h tile ----
  __syncthreads();  // all phase-A reads of hHi/hLo complete
  float fv[4][2][4], hvv[4][2][4];
#pragma unroll
  for (int rt = 0; rt < 4; ++rt)
#pragma unroll
    for (int ct = 0; ct < 2; ++ct) {
      int j = (2 * w + ct) * 16 + lj;
#pragma unroll
      for (int r = 0; r < 4; ++r) {
        int nl = rt * 16 + q * 4 + r;
        float z = acc[rt][ct][r] + bfj[ct];
        float f = sigmoid_f(z);
        int he = nl * LDST + j;
        float hval = (float)hHi[he] + (float)hLo[he];
        float g = f * hval;
        __bf16 ghi = (__bf16)g;
        hHi[he] = ghi;
        hLo[he] = (__bf16)(g - (float)ghi);
        fv[rt][ct][r] = f;
        hvv[rt][ct][r] = hval;
        acc[rt][ct][r] = 0.f;
      }
    }
  __syncthreads();

  // ---- phase B: z_h = m@Wh.T + g@Uh.T ----
#pragma unroll
  for (int kc = 0; kc < 128; kc += 32) {
    bf16x8 bwh[2], bwl[2], buh[2], bul[2];
#pragma unroll
    for (int ct = 0; ct < 2; ++ct) {
      int off = ((2 * w + ct) * 16 + lj) * 128 + kc + q * 8;
      bwh[ct] = *(const bf16x8*)&Whi[2 * 16384 + off];
      bwl[ct] = *(const bf16x8*)&Wlo[2 * 16384 + off];
      buh[ct] = *(const bf16x8*)&Whi[3 * 16384 + off];
      bul[ct] = *(const bf16x8*)&Wlo[3 * 16384 + off];
    }
#pragma unroll
    for (int rt = 0; rt < 4; ++rt) {
      int e0 = (rt * 16 + lj) * LDST + kc + q * 8;
      bf16x8 amh = *(const bf16x8*)&mHi[e0];
      bf16x8 aml = *(const bf16x8*)&mLo[e0];
      bf16x8 agh = *(const bf16x8*)&hHi[e0];
      bf16x8 agl = *(const bf16x8*)&hLo[e0];
#pragma unroll
      for (int ct = 0; ct < 2; ++ct) {
        f32x4 a = acc[rt][ct];
        a = __builtin_amdgcn_mfma_f32_16x16x32_bf16(amh, bwh[ct], a, 0, 0, 0);
        a = __builtin_amdgcn_mfma_f32_16x16x32_bf16(amh, bwl[ct], a, 0, 0, 0);
        a = __builtin_amdgcn_mfma_f32_16x16x32_bf16(aml, bwh[ct], a, 0, 0, 0);
        a = __builtin_amdgcn_mfma_f32_16x16x32_bf16(agh, buh[ct], a, 0, 0, 0);
        a = __builtin_amdgcn_mfma_f32_16x16x32_bf16(agh, bul[ct], a, 0, 0, 0);
        a = __builtin_amdgcn_mfma_f32_16x16x32_bf16(agl, buh[ct], a, 0, 0, 0);
        acc[rt][ct] = a;
      }
    }
  }

  // ---- epilogue: h = (1-f)*h + f*tanh(z_h + bh) ----
#pragma unroll
  for (int rt = 0; rt < 4; ++rt)
#pragma unroll
    for (int ct = 0; ct < 2; ++ct) {
      int j = (2 * w + ct) * 16 + lj;
#pragma unroll
      for (int r = 0; r < 4; ++r) {
        float T = tanh_f(acc[rt][ct][r] + bhj[ct]);
        float f = fv[rt][ct][r];
        float hn = (1.f - f) * hvv[rt][ct][r] + f * T;
        h[(nb + rt * 16 + q * 4 + r) * 128 + j] = hn;
      }
    }
}

// ---------------------------------------------------------------------------
// Whole Set2Set in ONE kernel, flash-style fused attention, unroll-2 streams.
// ---------------------------------------------------------------------------
__global__ __launch_bounds__(1024) void k_s2s(const float* __restrict__ h,
                                              const int* __restrict__ batch,
                                              const float* __restrict__ w_ih,
                                              const float* __restrict__ w_hh,
                                              const float* __restrict__ b_ih,
                                              const float* __restrict__ b_hh,
                                              const float* __restrict__ Wp,
                                              const float* __restrict__ bp,
                                              float* __restrict__ out) {
  const int g = blockIdx.x, t = threadIdx.x;
  const int w = t >> 6, l = t & 63;
  const int half = l >> 5, li = l & 31;
  const int hw = 2 * w + half;           // stream id 0..31
  __shared__ float qs[256];              // q_star = [q | r]
  __shared__ float hl[128], cl[128];
  __shared__ float gates[512];
  __shared__ float redM[32], redS[32], scl[32];
  __shared__ float rPart[32][132];       // row stride 528 B (16B aligned)
  __shared__ float gInvS;
  __shared__ int bnd[2];

  if (t < 2) {
    int tgt = g + t;
    int lo = 0, hi = N_NODES;
    while (lo < hi) { int mid = (lo + hi) >> 1; if (batch[mid] < tgt) lo = mid + 1; else hi = mid; }
    bnd[t] = lo;
  }
  if (t < 256) qs[t] = 0.f;
  if (t < 128) { hl[t] = 0.f; cl[t] = 0.f; }
  __syncthreads();
  const int s0 = bnd[0], s1 = bnd[1];

  for (int step = 0; step < 3; ++step) {
    // ---- LSTM gates: [512] = q_star@w_ih.T + h_l@w_hh.T + biases ----
#pragma unroll 2
    for (int jt = w; jt < 512; jt += 16) {
      const float* wi = w_ih + jt * 256;
      const float* wh = w_hh + jt * 128;
      float s = qs[l] * wi[l] + qs[l+64] * wi[l+64]
              + qs[l+128] * wi[l+128] + qs[l+192] * wi[l+192]
              + hl[l] * wh[l] + hl[l+64] * wh[l+64];
#pragma unroll
      for (int o = 32; o > 0; o >>= 1) s += __shfl_xor(s, o, 64);
      if (l == 0) gates[jt] = s + b_ih[jt] + b_hh[jt];
    }
    __syncthreads();
    if (t < 128) {
      float gi = gates[t], gf = gates[128 + t], gg = gates[256 + t], go = gates[384 + t];
      float c = sigmoid_f(gf) * cl[t] + sigmoid_f(gi) * tanh_f(gg);
      float hh = sigmoid_f(go) * tanh_f(c);
      cl[t] = c;
      hl[t] = hh;
      qs[t] = hh;  // q part
    }
    __syncthreads();

    // ---- fused attention (online softmax, single pass, 2 nodes in flight) ----
    float mw = -INFINITY, sw = 0.f;
    float4 racc = {0.f, 0.f, 0.f, 0.f};
    const float4* h4 = (const float4*)h;
    const float q0 = qs[4*li], q1 = qs[4*li+1], q2 = qs[4*li+2], q3 = qs[4*li+3];
    int n = s0 + hw;
    for (; n + 32 < s1; n += 64) {
      float4 hv0 = h4[n * 32 + li];
      float4 hv1 = h4[(n + 32) * 32 + li];
      float v0 = hv0.x * q0 + hv0.y * q1 + hv0.z * q2 + hv0.w * q3;
      float v1 = hv1.x * q0 + hv1.y * q1 + hv1.z * q2 + hv1.w * q3;
#pragma unroll
      for (int o = 16; o > 0; o >>= 1) {
        v0 += __shfl_xor(v0, o, 64);
        v1 += __shfl_xor(v1, o, 64);
      }
      float nm = fmaxf(mw, fmaxf(v0, v1));
      float sc = __expf(mw - nm);
      float w0 = __expf(v0 - nm);
      float w1 = __expf(v1 - nm);
      sw = sw * sc + w0 + w1;
      racc.x = racc.x * sc + w0 * hv0.x + w1 * hv1.x;
      racc.y = racc.y * sc + w0 * hv0.y + w1 * hv1.y;
      racc.z = racc.z * sc + w0 * hv0.z + w1 * hv1.z;
      racc.w = racc.w * sc + w0 * hv0.w + w1 * hv1.w;
      mw = nm;
    }
    for (; n < s1; n += 32) {
      float4 hv = h4[n * 32 + li];
      float v = hv.x * q0 + hv.y * q1 + hv.z * q2 + hv.w * q3;
#pragma unroll
      for (int o = 16; o > 0; o >>= 1) v += __shfl_xor(v, o, 64);
      float nm = fmaxf(mw, v);
      float sc = __expf(mw - nm);
      float wg = __expf(v - nm);
      sw = sw * sc + wg;
      racc.x = racc.x * sc + wg * hv.x;
      racc.y = racc.y * sc + wg * hv.y;
      racc.z = racc.z * sc + wg * hv.z;
      racc.w = racc.w * sc + wg * hv.w;
      mw = nm;
    }
    if (li == 0) { redM[hw] = mw; redS[hw] = sw; }
    *(float4*)&rPart[hw][4 * li] = racc;
    __syncthreads();
    if (t == 0) {
      float M = -INFINITY;
      for (int i = 0; i < 32; ++i) M = fmaxf(M, redM[i]);
      float S = 0.f;
      for (int i = 0; i < 32; ++i) {
        float s_ = (redM[i] > -INFINITY && M > -INFINITY) ? __expf(redM[i] - M) : 0.f;
        scl[i] = s_;
        S += redS[i] * s_;
      }
      gInvS = (S > 0.f) ? __fdividef(1.f, S) : 0.f;
    }
    __syncthreads();
    if (t < 128) {
      float inv = gInvS;
      float r = 0.f;
#pragma unroll
      for (int i = 0; i < 32; ++i) r += rPart[i][t] * scl[i];
      qs[128 + t] = r * inv;
    }
    __syncthreads();
  }

  // ---- prediction: out[g] = <q_star, W_pred> + b ----
  __shared__ float pr[256];
  if (t < 256) pr[t] = qs[t] * Wp[t];
  __syncthreads();
  if (t < 128) pr[t] += pr[t + 128];
  __syncthreads();
  if (t < 64) {
    float s = pr[t] + pr[t + 64];
#pragma unroll
    for (int o = 32; o > 0; o >>= 1) s += __shfl_xor(s, o, 64);
    if (t == 0) out[g] = s + bp[0];
  }
}

// ---------------------------------------------------------------------------
extern "C" void kernel_launch(void* const* d_in, const int* in_sizes, int n_in,
                              void* d_out, int out_size, void* d_ws, size_t ws_size,
                              hipStream_t stream) {
  const float* x      = (const float*)d_in[0];
  const int*   ei     = (const int*)d_in[1];
  const int*   batch  = (const int*)d_in[2];
  const float* W_in   = (const float*)d_in[3];
  const float* b_in   = (const float*)d_in[4];
  const float* W_f    = (const float*)d_in[5];
  const float* U_f    = (const float*)d_in[6];
  const float* b_f    = (const float*)d_in[7];
  const float* W_h    = (const float*)d_in[8];
  const float* U_h    = (const float*)d_in[9];
  const float* b_h    = (const float*)d_in[10];
  const float* w_ih   = (const float*)d_in[11];
  const float* w_hh   = (const float*)d_in[12];
  const float* b_ih   = (const float*)d_in[13];
  const float* b_hh   = (const float*)d_in[14];
  const float* W_pred = (const float*)d_in[15];
  const float* b_pred = (const float*)d_in[16];
  float* out = (float*)d_out;

  char* ws = (char*)d_ws;
  float* h      = (float*)(ws);                    // 51,200,000 B
  float* m      = (float*)(ws + 51200000);         // 51,200,000 B
  int*   rowstart = (int*)(ws + 103063808);        //    400,016 B
  int*   srcSorted= (int*)(ws + 103463824);        //  2,560,000 B
  int*   bsum   = (int*)  (ws + 106023824);        //        112 B
  int*   boff   = (int*)  (ws + 106023936);        //        112 B
  // region at +102,400,000 (400,000 B): deg/cursor (CSR build) then Whi/Wlo
  int*    deg    = (int*)(ws + 102400000);
  int*    cursor = (int*)(ws + 102400000);
  __bf16* Whi    = (__bf16*)(ws + 102400000);      //    131,072 B
  __bf16* Wlo    = (__bf16*)(ws + 102531072);      //    131,072 B

  const int* src = ei;
  const int* dst = ei + N_EDGES;

  // ---- CSR build (once; reused by all 3 MPNN steps) ----
  hipMemsetAsync(deg, 0, N_NODES * 4, stream);
  k_hist<<<(N_EDGES + 255) / 256, 256, 0, stream>>>(dst, deg);
  k_scan_part<<<SCAN_NB, 256, 0, stream>>>(deg, bsum);
  k_scan_mid<<<1, 32, 0, stream>>>(bsum, boff, rowstart);
  k_scan_final<<<SCAN_NB, 256, 0, stream>>>(deg, boff, rowstart);
  hipMemcpyAsync(cursor, rowstart, N_NODES * 4, hipMemcpyDeviceToDevice, stream);
  k_fill<<<(N_EDGES + 255) / 256, 256, 0, stream>>>(src, dst, cursor, srcSorted);

  // ---- one-time weight bf16 hi/lo split (overwrites deg/cursor region) ----
  k_wsplit<<<256, 256, 0, stream>>>(W_f, U_f, W_h, U_h, Whi, Wlo);

  k_input<<<N_NODES / 32, 256, 0, stream>>>(x, W_in, b_in, h);

  for (int step = 0; step < 3; ++step) {
    k_gather<<<(N_NODES + 7) / 8, 256, 0, stream>>>(h, rowstart, srcSorted, m);
    k_mgu<<<(N_NODES + 63) / 64, 256, 0, stream>>>(h, m, Whi, Wlo, b_f, b_h);
  }

  // ---- entire Set2Set + prediction in one launch ----
  k_s2s<<<NGRAPH, 1024, 0, stream>>>(h, batch, w_ih, w_hh, b_ih, b_hh,
                                     W_pred, b_pred, out);
}